// Round 2
// baseline (1621.294 us; speedup 1.0000x reference)
//
#include <hip/hip_runtime.h>

#define BATCH   2
#define LSEQ    4096
#define DMODEL  1024
#define DINNER  2048
#define NHEADS  16
#define DSTATE  64
#define HEADDIM 128
#define ZDIM    4112
#define BLROWS  (BATCH*LSEQ)   // 8192
#define NPAD_IN 4224           // 4112 padded to 33*128

typedef __bf16 bf16;
typedef __bf16 bf16x8 __attribute__((ext_vector_type(8)));
typedef __bf16 bf16x4 __attribute__((ext_vector_type(4)));
typedef float  f32x4  __attribute__((ext_vector_type(4)));

// ---------------- fp32 -> bf16 convert (vectorized) ----------------
__global__ void cvt_bf16_kernel(const float* __restrict__ in, bf16* __restrict__ out, int n)
{
    int i = (blockIdx.x * 256 + threadIdx.x) * 4;
    if (i >= n) return;
    float4 v = *reinterpret_cast<const float4*>(in + i);
    bf16x4 o;
    o[0] = (bf16)v.x; o[1] = (bf16)v.y; o[2] = (bf16)v.z; o[3] = (bf16)v.w;
    *reinterpret_cast<bf16x4*>(out + i) = o;
}

// ---------------- transpose + convert: src[R][C] f32 -> dst[Cpad][R] bf16 ----------------
__global__ void transpose_cvt_kernel(const float* __restrict__ src, bf16* __restrict__ dst,
                                     int R, int C, int Cpad)
{
    __shared__ float tile[32][33];
    int tx = threadIdx.x;   // 0..31
    int ty = threadIdx.y;   // 0..7
    int c0 = blockIdx.x * 32;
    int r0 = blockIdx.y * 32;
#pragma unroll
    for (int q = 0; q < 4; q++) {
        int r = r0 + ty + q * 8;
        int c = c0 + tx;
        float v = 0.f;
        if (r < R && c < C) v = src[(size_t)r * C + c];
        tile[ty + q * 8][tx] = v;
    }
    __syncthreads();
#pragma unroll
    for (int q = 0; q < 4; q++) {
        int oc = c0 + ty + q * 8;   // output row (= original col)
        int orr = r0 + tx;          // output col (= original row)
        if (oc < Cpad && orr < R)
            dst[(size_t)oc * R + orr] = (bf16)tile[tx][ty + q * 8];
    }
}

// ---------------- bf16 MFMA GEMM: C[M][Ns] = A[M][K] * Bt[Npad][K]^T ----------------
// BF16OUT: store bf16 instead of f32. HASDT: also store f32 for cols [4096,4112)
template<bool BF16OUT, bool HASDT>
__global__ __launch_bounds__(256) void gemm_bf16_kernel(
    const bf16* __restrict__ A,   // [M][K] row-major
    const bf16* __restrict__ Bt,  // [Npad][K] row-major (B transposed)
    void* __restrict__ Cout,      // [M][Ns]
    float* __restrict__ dtout,    // [M][16] f32 sidecar (HASDT only)
    int K, int Ns, int Nstore)
{
    __shared__ __align__(16) bf16 As[128 * 32];
    __shared__ __align__(16) bf16 Bs[128 * 32];
    const int t = threadIdx.x;
    const int bm = blockIdx.y, bn = blockIdx.x;
    const int w = t >> 6, lane = t & 63;
    const int wm = (w >> 1) * 64, wn = (w & 1) * 64;
    const int lm = lane & 15, lk = (lane >> 4) * 8;

    const bf16* Ab = A + (size_t)(bm * 128) * K;
    const bf16* Bb = Bt + (size_t)(bn * 128) * K;

    const int e0 = t * 8;
    const int r0s = e0 >> 5, k0s = e0 & 31;
    const int e1 = e0 + 2048;
    const int r1s = e1 >> 5, k1s = e1 & 31;

    f32x4 acc[4][4];
#pragma unroll
    for (int i = 0; i < 4; i++)
#pragma unroll
        for (int j = 0; j < 4; j++) acc[i][j] = (f32x4){0.f, 0.f, 0.f, 0.f};

    for (int k0 = 0; k0 < K; k0 += 32) {
        __builtin_amdgcn_global_load_lds(
            (const __attribute__((address_space(1))) void*)(Ab + (size_t)r0s * K + k0 + k0s),
            (__attribute__((address_space(3))) void*)(&As[e0]), 16, 0, 0);
        __builtin_amdgcn_global_load_lds(
            (const __attribute__((address_space(1))) void*)(Ab + (size_t)r1s * K + k0 + k1s),
            (__attribute__((address_space(3))) void*)(&As[e1]), 16, 0, 0);
        __builtin_amdgcn_global_load_lds(
            (const __attribute__((address_space(1))) void*)(Bb + (size_t)r0s * K + k0 + k0s),
            (__attribute__((address_space(3))) void*)(&Bs[e0]), 16, 0, 0);
        __builtin_amdgcn_global_load_lds(
            (const __attribute__((address_space(1))) void*)(Bb + (size_t)r1s * K + k0 + k1s),
            (__attribute__((address_space(3))) void*)(&Bs[e1]), 16, 0, 0);
        __syncthreads();

        bf16x8 af[4], bfr[4];
#pragma unroll
        for (int i = 0; i < 4; i++)
            af[i] = *reinterpret_cast<const bf16x8*>(&As[(wm + i * 16 + lm) * 32 + lk]);
#pragma unroll
        for (int j = 0; j < 4; j++)
            bfr[j] = *reinterpret_cast<const bf16x8*>(&Bs[(wn + j * 16 + lm) * 32 + lk]);
#pragma unroll
        for (int i = 0; i < 4; i++)
#pragma unroll
            for (int j = 0; j < 4; j++)
                acc[i][j] = __builtin_amdgcn_mfma_f32_16x16x32_bf16(af[i], bfr[j], acc[i][j], 0, 0, 0);
        __syncthreads();
    }

    const int rrow = (lane >> 4) * 4;
    const int ccol = lane & 15;
#pragma unroll
    for (int i = 0; i < 4; i++) {
#pragma unroll
        for (int j = 0; j < 4; j++) {
            int col = bn * 128 + wn + j * 16 + ccol;
            if (col < Nstore) {
#pragma unroll
                for (int r = 0; r < 4; r++) {
                    int row = bm * 128 + wm + i * 16 + rrow + r;
                    float v = acc[i][j][r];
                    if constexpr (BF16OUT)
                        ((bf16*)Cout)[(size_t)row * Ns + col] = (bf16)v;
                    else
                        ((float*)Cout)[(size_t)row * Ns + col] = v;
                    if constexpr (HASDT) {
                        if (col >= DINNER + 2048)
                            dtout[(size_t)row * NHEADS + (col - (DINNER + 2048))] = v;
                    }
                }
            }
        }
    }
}

// ---------------- causal depthwise conv (D_CONV=4) + SiLU ----------------
__global__ void conv_silu_kernel(const bf16* __restrict__ z, const float* __restrict__ conv_w,
                                 const float* __restrict__ conv_b, bf16* __restrict__ x)
{
    int gid = blockIdx.x * 256 + threadIdx.x;
    if (gid >= BLROWS * DINNER) return;
    int c = gid & (DINNER - 1);
    int bl = gid >> 11;
    int l = bl & (LSEQ - 1);
    float4 w4 = *reinterpret_cast<const float4*>(conv_w + (size_t)c * 4);
    float acc = conv_b[c];
    if (l - 3 >= 0) acc += (float)z[(size_t)(bl - 3) * ZDIM + c] * w4.x;
    if (l - 2 >= 0) acc += (float)z[(size_t)(bl - 2) * ZDIM + c] * w4.y;
    if (l - 1 >= 0) acc += (float)z[(size_t)(bl - 1) * ZDIM + c] * w4.z;
    acc += (float)z[(size_t)bl * ZDIM + c] * w4.w;
    x[(size_t)gid] = (bf16)(acc / (1.f + expf(-acc)));   // silu
}

// ---------------- a_bar = exp(-softplus(dt+dp)*|dt|) from f32 dt sidecar ----------------
__global__ void abar_kernel(const float* __restrict__ dt_in, const float* __restrict__ dparam,
                            float* __restrict__ abar)
{
    int i = blockIdx.x * 256 + threadIdx.x;
    if (i >= BLROWS * NHEADS) return;
    int h = i & (NHEADS - 1);
    float dt = dt_in[i];
    float v = dt + dparam[h];
    float sp = (v > 20.f) ? v : log1pf(expf(v));
    abar[i] = expf(-sp * fabsf(dt));
}

// ---------------- sequential SSM scan ----------------
// grid: B*NH*4 = 128 blocks of 512 threads. Each wave is self-contained:
// lanes = 4 d-values x 16 s-slices (4 states each). No barriers; depth-2 prefetch.
// y (bf16) is written IN-PLACE over x (read of x[l] happens 2 steps before write of y[l]).
__global__ __launch_bounds__(512) void scan_kernel(
    bf16* xy,                        // [BL][2048]: x in, y out (same storage)
    const bf16* __restrict__ zb,     // B at col 2048+h*64, C at +1024 (stride ZDIM)
    const float* __restrict__ abar)  // [BL][16]
{
    int blk = blockIdx.x;
    int dq = blk & 3;
    int h  = (blk >> 2) & (NHEADS - 1);
    int b  = blk >> 6;
    int t  = threadIdx.x;
    int dd = t >> 4;            // 0..31
    int sl = t & 15;
    int d  = dq * 32 + dd;
    int s0 = sl * 4;

    size_t rowbase = (size_t)b * LSEQ;
    bf16* xp = xy + rowbase * DINNER + h * HEADDIM + d;
    const bf16* Bp = zb + rowbase * ZDIM + DINNER + h * DSTATE + s0;
    const bf16* Cp = Bp + NHEADS * DSTATE;
    const float* ap = abar + rowbase * NHEADS + h;

    float h0 = 0.f, h1 = 0.f, h2 = 0.f, h3 = 0.f;

    float a0, xv0, a1, xv1;
    float4 B0, C0, B1, C1;
#define LOADSTEP(l, a, xv, Bv, Cv)                                           \
    {                                                                        \
        int _l = (l); if (_l > LSEQ - 1) _l = LSEQ - 1;                      \
        a  = ap[(size_t)_l * NHEADS];                                        \
        xv = (float)xp[(size_t)_l * DINNER];                                 \
        bf16x4 _b = *reinterpret_cast<const bf16x4*>(Bp + (size_t)_l * ZDIM);\
        bf16x4 _c = *reinterpret_cast<const bf16x4*>(Cp + (size_t)_l * ZDIM);\
        Bv = make_float4((float)_b[0], (float)_b[1], (float)_b[2], (float)_b[3]); \
        Cv = make_float4((float)_c[0], (float)_c[1], (float)_c[2], (float)_c[3]); \
    }
    LOADSTEP(0, a0, xv0, B0, C0);
    LOADSTEP(1, a1, xv1, B1, C1);

    for (int l = 0; l < LSEQ; l += 2) {
        float na, nx; float4 nB, nC;
        LOADSTEP(l + 2, na, nx, nB, nC);
        {
            h0 = a0 * h0 + xv0 * B0.x;
            h1 = a0 * h1 + xv0 * B0.y;
            h2 = a0 * h2 + xv0 * B0.z;
            h3 = a0 * h3 + xv0 * B0.w;
            float yv = h0 * C0.x + h1 * C0.y + h2 * C0.z + h3 * C0.w;
            yv += __shfl_xor(yv, 1);
            yv += __shfl_xor(yv, 2);
            yv += __shfl_xor(yv, 4);
            yv += __shfl_xor(yv, 8);
            if (sl == 0) xp[(size_t)l * DINNER] = (bf16)yv;
        }
        a0 = na; xv0 = nx; B0 = nB; C0 = nC;

        LOADSTEP(l + 3, na, nx, nB, nC);
        {
            h0 = a1 * h0 + xv1 * B1.x;
            h1 = a1 * h1 + xv1 * B1.y;
            h2 = a1 * h2 + xv1 * B1.z;
            h3 = a1 * h3 + xv1 * B1.w;
            float yv = h0 * C1.x + h1 * C1.y + h2 * C1.z + h3 * C1.w;
            yv += __shfl_xor(yv, 1);
            yv += __shfl_xor(yv, 2);
            yv += __shfl_xor(yv, 4);
            yv += __shfl_xor(yv, 8);
            if (sl == 0) xp[(size_t)(l + 1) * DINNER] = (bf16)yv;
        }
        a1 = na; xv1 = nx; B1 = nB; C1 = nC;
    }
#undef LOADSTEP
}

// ---------------- gate (sigmoid) * y, RMS norm, -> bf16 (in-place over g) ----------------
__global__ __launch_bounds__(256) void gate_rms_kernel(
    const bf16* __restrict__ y,   // [BL][2048]
    bf16* g,                      // [BL][2048]: gate pre-act in, normalized y out
    const float* __restrict__ norm_w)
{
    __shared__ float red[4];
    int row = blockIdx.x, t = threadIdx.x;
    const bf16* yr = y + (size_t)row * DINNER;
    bf16* gr = g + (size_t)row * DINNER;
    int c0 = t * 8;
    bf16x8 yv8 = *reinterpret_cast<const bf16x8*>(yr + c0);
    bf16x8 gv8 = *reinterpret_cast<const bf16x8*>(gr + c0);
    float v[8];
#pragma unroll
    for (int i = 0; i < 8; i++) {
        float yf = (float)yv8[i];
        float gf = (float)gv8[i];
        v[i] = yf / (1.f + expf(-gf));
    }
    float ss = 0.f;
#pragma unroll
    for (int i = 0; i < 8; i++) ss += v[i] * v[i];
#pragma unroll
    for (int off = 32; off >= 1; off >>= 1) ss += __shfl_xor(ss, off);
    if ((t & 63) == 0) red[t >> 6] = ss;
    __syncthreads();
    ss = red[0] + red[1] + red[2] + red[3];
    float sc = rsqrtf(ss * (1.0f / DINNER) + 1.1920928955078125e-07f);
    float4 na = *reinterpret_cast<const float4*>(norm_w + c0);
    float4 nb = *reinterpret_cast<const float4*>(norm_w + c0 + 4);
    bf16x8 ov;
    ov[0] = (bf16)(v[0] * sc * na.x);
    ov[1] = (bf16)(v[1] * sc * na.y);
    ov[2] = (bf16)(v[2] * sc * na.z);
    ov[3] = (bf16)(v[3] * sc * na.w);
    ov[4] = (bf16)(v[4] * sc * nb.x);
    ov[5] = (bf16)(v[5] * sc * nb.y);
    ov[6] = (bf16)(v[6] * sc * nb.z);
    ov[7] = (bf16)(v[7] * sc * nb.w);
    *reinterpret_cast<bf16x8*>(gr + c0) = ov;
}

// ---------------- launch ----------------
extern "C" void kernel_launch(void* const* d_in, const int* in_sizes, int n_in,
                              void* d_out, int out_size, void* d_ws, size_t ws_size,
                              hipStream_t stream)
{
    const float* u      = (const float*)d_in[0];
    const float* W_in   = (const float*)d_in[1];
    const float* conv_w = (const float*)d_in[2];
    const float* conv_b = (const float*)d_in[3];
    const float* dparam = (const float*)d_in[4];
    const float* W_gate = (const float*)d_in[5];
    const float* norm_w = (const float*)d_in[6];
    const float* W_out  = (const float*)d_in[7];
    float* out = (float*)d_out;

    char* ws = (char*)d_ws;
    size_t off = 0;
    auto alloc = [&](size_t bytes) {
        void* p = ws + off;
        off += (bytes + 255) & ~(size_t)255;
        return p;
    };
    // total ws use: ~135.9 MB
    bf16*  u_bf  = (bf16*) alloc((size_t)BLROWS * DMODEL * 2);   // 16.8 MB
    bf16*  Wt_in = (bf16*) alloc((size_t)NPAD_IN * DMODEL * 2);  // 8.7 MB
    bf16*  Wt_g  = (bf16*) alloc((size_t)DINNER * DMODEL * 2);   // 4.2 MB
    bf16*  Wt_o  = (bf16*) alloc((size_t)DMODEL * DINNER * 2);   // 4.2 MB
    bf16*  z     = (bf16*) alloc((size_t)BLROWS * ZDIM * 2);     // 67.4 MB
    bf16*  g     = (bf16*) alloc((size_t)BLROWS * DINNER * 2);   // 33.6 MB (yn in-place)
    float* dt    = (float*)alloc((size_t)BLROWS * NHEADS * 4);   // 0.5 MB
    float* abar  = (float*)alloc((size_t)BLROWS * NHEADS * 4);   // 0.5 MB
    // x/y live in d_out (33.5 MB, fully overwritten by the final GEMM)
    bf16* xy = (bf16*)d_out;
    (void)ws_size; (void)in_sizes; (void)n_in; (void)out_size;

    dim3 tb(32, 8);
    cvt_bf16_kernel<<<(BLROWS * DMODEL / 4 + 255) / 256, 256, 0, stream>>>(u, u_bf, BLROWS * DMODEL);
    transpose_cvt_kernel<<<dim3(NPAD_IN / 32, DMODEL / 32), tb, 0, stream>>>(W_in, Wt_in, DMODEL, ZDIM, NPAD_IN);
    transpose_cvt_kernel<<<dim3(DINNER / 32, DMODEL / 32), tb, 0, stream>>>(W_gate, Wt_g, DMODEL, DINNER, DINNER);
    transpose_cvt_kernel<<<dim3(DMODEL / 32, DINNER / 32), tb, 0, stream>>>(W_out, Wt_o, DINNER, DMODEL, DMODEL);

    // z = u @ W_in (bf16 out + f32 dt sidecar)   M=8192, K=1024, N=4112 (pad 4224)
    gemm_bf16_kernel<true, true><<<dim3(NPAD_IN / 128, BLROWS / 128), 256, 0, stream>>>(
        u_bf, Wt_in, z, dt, DMODEL, ZDIM, ZDIM);
    // g = u @ W_gate (bf16 out)                  N=2048
    gemm_bf16_kernel<true, false><<<dim3(DINNER / 128, BLROWS / 128), 256, 0, stream>>>(
        u_bf, Wt_g, g, nullptr, DMODEL, DINNER, DINNER);

    conv_silu_kernel<<<(BLROWS * DINNER + 255) / 256, 256, 0, stream>>>(z, conv_w, conv_b, xy);
    abar_kernel<<<(BLROWS * NHEADS + 255) / 256, 256, 0, stream>>>(dt, dparam, abar);

    scan_kernel<<<BATCH * NHEADS * 4, 512, 0, stream>>>(xy, z, abar);

    gate_rms_kernel<<<BLROWS, 256, 0, stream>>>(xy, g, norm_w);

    // out = yn @ W_out (f32 out)   M=8192, K=2048, N=1024 — overwrites xy region
    gemm_bf16_kernel<false, false><<<dim3(DMODEL / 128, BLROWS / 128), 256, 0, stream>>>(
        g, Wt_o, out, nullptr, DINNER, DMODEL, DMODEL);
}

// Round 3
// 510.269 us; speedup vs baseline: 3.1773x; 3.1773x over previous
//
#include <hip/hip_runtime.h>

#define BATCH   2
#define LSEQ    4096
#define DMODEL  1024
#define DINNER  2048
#define NHEADS  16
#define DSTATE  64
#define HEADDIM 128
#define ZDIM    4112
#define BLROWS  (BATCH*LSEQ)   // 8192
#define NPAD_IN 4224           // 4112 padded to 33*128
#define QCHUNK  64
#define NCHUNK  (LSEQ/QCHUNK)  // 64

typedef __bf16 bf16;
typedef __bf16 bf16x8 __attribute__((ext_vector_type(8)));
typedef __bf16 bf16x4 __attribute__((ext_vector_type(4)));
typedef float  f32x4  __attribute__((ext_vector_type(4)));

// ---------------- fp32 -> bf16 convert (vectorized) ----------------
__global__ void cvt_bf16_kernel(const float* __restrict__ in, bf16* __restrict__ out, int n)
{
    int i = (blockIdx.x * 256 + threadIdx.x) * 4;
    if (i >= n) return;
    float4 v = *reinterpret_cast<const float4*>(in + i);
    bf16x4 o;
    o[0] = (bf16)v.x; o[1] = (bf16)v.y; o[2] = (bf16)v.z; o[3] = (bf16)v.w;
    *reinterpret_cast<bf16x4*>(out + i) = o;
}

// ---------------- transpose + convert: src[R][C] f32 -> dst[Cpad][R] bf16 ----------------
__global__ void transpose_cvt_kernel(const float* __restrict__ src, bf16* __restrict__ dst,
                                     int R, int C, int Cpad)
{
    __shared__ float tile[32][33];
    int tx = threadIdx.x;   // 0..31
    int ty = threadIdx.y;   // 0..7
    int c0 = blockIdx.x * 32;
    int r0 = blockIdx.y * 32;
#pragma unroll
    for (int q = 0; q < 4; q++) {
        int r = r0 + ty + q * 8;
        int c = c0 + tx;
        float v = 0.f;
        if (r < R && c < C) v = src[(size_t)r * C + c];
        tile[ty + q * 8][tx] = v;
    }
    __syncthreads();
#pragma unroll
    for (int q = 0; q < 4; q++) {
        int oc = c0 + ty + q * 8;   // output row (= original col)
        int orr = r0 + tx;          // output col (= original row)
        if (oc < Cpad && orr < R)
            dst[(size_t)oc * R + orr] = (bf16)tile[tx][ty + q * 8];
    }
}

// ---------------- bf16 MFMA GEMM: C[M][Ns] = A[M][K] * Bt[Npad][K]^T ----------------
template<bool BF16OUT, bool HASDT>
__global__ __launch_bounds__(256) void gemm_bf16_kernel(
    const bf16* __restrict__ A,   // [M][K] row-major
    const bf16* __restrict__ Bt,  // [Npad][K] row-major (B transposed)
    void* __restrict__ Cout,      // [M][Ns]
    float* __restrict__ dtout,    // [M][16] f32 sidecar (HASDT only)
    int K, int Ns, int Nstore)
{
    __shared__ __align__(16) bf16 As[128 * 32];
    __shared__ __align__(16) bf16 Bs[128 * 32];
    const int t = threadIdx.x;
    const int bm = blockIdx.y, bn = blockIdx.x;
    const int w = t >> 6, lane = t & 63;
    const int wm = (w >> 1) * 64, wn = (w & 1) * 64;
    const int lm = lane & 15, lk = (lane >> 4) * 8;

    const bf16* Ab = A + (size_t)(bm * 128) * K;
    const bf16* Bb = Bt + (size_t)(bn * 128) * K;

    const int e0 = t * 8;
    const int r0s = e0 >> 5, k0s = e0 & 31;
    const int e1 = e0 + 2048;
    const int r1s = e1 >> 5, k1s = e1 & 31;

    f32x4 acc[4][4];
#pragma unroll
    for (int i = 0; i < 4; i++)
#pragma unroll
        for (int j = 0; j < 4; j++) acc[i][j] = (f32x4){0.f, 0.f, 0.f, 0.f};

    for (int k0 = 0; k0 < K; k0 += 32) {
        __builtin_amdgcn_global_load_lds(
            (const __attribute__((address_space(1))) void*)(Ab + (size_t)r0s * K + k0 + k0s),
            (__attribute__((address_space(3))) void*)(&As[e0]), 16, 0, 0);
        __builtin_amdgcn_global_load_lds(
            (const __attribute__((address_space(1))) void*)(Ab + (size_t)r1s * K + k0 + k1s),
            (__attribute__((address_space(3))) void*)(&As[e1]), 16, 0, 0);
        __builtin_amdgcn_global_load_lds(
            (const __attribute__((address_space(1))) void*)(Bb + (size_t)r0s * K + k0 + k0s),
            (__attribute__((address_space(3))) void*)(&Bs[e0]), 16, 0, 0);
        __builtin_amdgcn_global_load_lds(
            (const __attribute__((address_space(1))) void*)(Bb + (size_t)r1s * K + k0 + k1s),
            (__attribute__((address_space(3))) void*)(&Bs[e1]), 16, 0, 0);
        __syncthreads();

        bf16x8 af[4], bfr[4];
#pragma unroll
        for (int i = 0; i < 4; i++)
            af[i] = *reinterpret_cast<const bf16x8*>(&As[(wm + i * 16 + lm) * 32 + lk]);
#pragma unroll
        for (int j = 0; j < 4; j++)
            bfr[j] = *reinterpret_cast<const bf16x8*>(&Bs[(wn + j * 16 + lm) * 32 + lk]);
#pragma unroll
        for (int i = 0; i < 4; i++)
#pragma unroll
            for (int j = 0; j < 4; j++)
                acc[i][j] = __builtin_amdgcn_mfma_f32_16x16x32_bf16(af[i], bfr[j], acc[i][j], 0, 0, 0);
        __syncthreads();
    }

    const int rrow = (lane >> 4) * 4;
    const int ccol = lane & 15;
#pragma unroll
    for (int i = 0; i < 4; i++) {
#pragma unroll
        for (int j = 0; j < 4; j++) {
            int col = bn * 128 + wn + j * 16 + ccol;
            if (col < Nstore) {
#pragma unroll
                for (int r = 0; r < 4; r++) {
                    int row = bm * 128 + wm + i * 16 + rrow + r;
                    float v = acc[i][j][r];
                    if constexpr (BF16OUT)
                        ((bf16*)Cout)[(size_t)row * Ns + col] = (bf16)v;
                    else
                        ((float*)Cout)[(size_t)row * Ns + col] = v;
                    if constexpr (HASDT) {
                        if (col >= DINNER + 2048)
                            dtout[(size_t)row * NHEADS + (col - (DINNER + 2048))] = v;
                    }
                }
            }
        }
    }
}

// ---------------- causal depthwise conv (D_CONV=4) + SiLU ----------------
__global__ void conv_silu_kernel(const bf16* __restrict__ z, const float* __restrict__ conv_w,
                                 const float* __restrict__ conv_b, bf16* __restrict__ x)
{
    int gid = blockIdx.x * 256 + threadIdx.x;
    if (gid >= BLROWS * DINNER) return;
    int c = gid & (DINNER - 1);
    int bl = gid >> 11;
    int l = bl & (LSEQ - 1);
    float4 w4 = *reinterpret_cast<const float4*>(conv_w + (size_t)c * 4);
    float acc = conv_b[c];
    if (l - 3 >= 0) acc += (float)z[(size_t)(bl - 3) * ZDIM + c] * w4.x;
    if (l - 2 >= 0) acc += (float)z[(size_t)(bl - 2) * ZDIM + c] * w4.y;
    if (l - 1 >= 0) acc += (float)z[(size_t)(bl - 1) * ZDIM + c] * w4.z;
    acc += (float)z[(size_t)bl * ZDIM + c] * w4.w;
    x[(size_t)gid] = (bf16)(acc / (1.f + expf(-acc)));   // silu
}

// ---------------- a_bar = exp(-softplus(dt+dp)*|dt|) from f32 dt sidecar ----------------
__global__ void abar_kernel(const float* __restrict__ dt_in, const float* __restrict__ dparam,
                            float* __restrict__ abar)
{
    int i = blockIdx.x * 256 + threadIdx.x;
    if (i >= BLROWS * NHEADS) return;
    int h = i & (NHEADS - 1);
    float dt = dt_in[i];
    float v = dt + dparam[h];
    float sp = (v > 20.f) ? v : log1pf(expf(v));
    abar[i] = expf(-sp * fabsf(dt));
}

// ================= chunked scan =================
// Pass 1: per (b,h,chunk) compute zero-seeded chunk-final state S_c [128][64]
// and decay product A_c. 256 thr: thread owns 4 d x 8 s.
__global__ __launch_bounds__(256) void chunk_state_kernel(
    const bf16* __restrict__ x,    // [BL][DINNER]
    const bf16* __restrict__ zb,   // B at col DINNER+h*64, stride ZDIM
    const float* __restrict__ abar,// [BL][16]
    bf16* __restrict__ S,          // [B][NCHUNK][NHEADS][128*64]
    float* __restrict__ A)         // [B][NHEADS][NCHUNK]
{
    __shared__ __align__(16) bf16 x_lds[QCHUNK * HEADDIM]; // 16 KB
    __shared__ __align__(16) bf16 B_lds[QCHUNK * DSTATE];  // 8 KB
    __shared__ float a_lds[QCHUNK];
    int blk = blockIdx.x;
    int h = blk & 15;
    int c = (blk >> 4) & (NCHUNK - 1);
    int b = blk >> 10;
    int tid = threadIdx.x;
    size_t row0 = (size_t)b * LSEQ + (size_t)c * QCHUNK;
    const bf16* xg = x + row0 * DINNER + h * HEADDIM;
    const bf16* Bg = zb + row0 * ZDIM + DINNER + h * DSTATE;

#pragma unroll
    for (int it = 0; it < 4; ++it) {
        int idx = it * 256 + tid;
        int r = idx >> 4, cc = (idx & 15) * 8;
        __builtin_amdgcn_global_load_lds(
            (const __attribute__((address_space(1))) void*)(xg + (size_t)r * DINNER + cc),
            (__attribute__((address_space(3))) void*)(&x_lds[idx * 8]), 16, 0, 0);
    }
#pragma unroll
    for (int it = 0; it < 2; ++it) {
        int idx = it * 256 + tid;
        int r = idx >> 3, cc = (idx & 7) * 8;
        __builtin_amdgcn_global_load_lds(
            (const __attribute__((address_space(1))) void*)(Bg + (size_t)r * ZDIM + cc),
            (__attribute__((address_space(3))) void*)(&B_lds[idx * 8]), 16, 0, 0);
    }
    if (tid < QCHUNK) a_lds[tid] = abar[(row0 + tid) * NHEADS + h];
    __syncthreads();

    int sg = tid & 7, dg = tid >> 3;
    int s0 = sg * 8, d0 = dg * 4;
    float hs[4][8];
#pragma unroll
    for (int i = 0; i < 4; i++)
#pragma unroll
        for (int j = 0; j < 8; j++) hs[i][j] = 0.f;

    for (int t = 0; t < QCHUNK; ++t) {
        float a = a_lds[t];
        bf16x4 xv = *reinterpret_cast<const bf16x4*>(&x_lds[t * HEADDIM + d0]);
        bf16x8 bv = *reinterpret_cast<const bf16x8*>(&B_lds[t * DSTATE + s0]);
        float xf[4], bfv[8];
#pragma unroll
        for (int i = 0; i < 4; i++) xf[i] = (float)xv[i];
#pragma unroll
        for (int j = 0; j < 8; j++) bfv[j] = (float)bv[j];
#pragma unroll
        for (int i = 0; i < 4; i++)
#pragma unroll
            for (int j = 0; j < 8; j++)
                hs[i][j] = fmaf(a, hs[i][j], xf[i] * bfv[j]);
    }

    if (tid == 0) {
        float pa = 1.f;
        for (int t = 0; t < QCHUNK; ++t) pa *= a_lds[t];
        A[((size_t)b * NHEADS + h) * NCHUNK + c] = pa;
    }

    bf16* Sg = S + ((size_t)(b * NCHUNK + c) * NHEADS + h) * (HEADDIM * DSTATE);
#pragma unroll
    for (int i = 0; i < 4; i++) {
        bf16x8 o;
#pragma unroll
        for (int j = 0; j < 8; j++) o[j] = (bf16)hs[i][j];
        *reinterpret_cast<bf16x8*>(&Sg[(d0 + i) * DSTATE + s0]) = o;
    }
}

// Pass 1b: inter-chunk carry, in-place: S_c is replaced by H_c (state at chunk START).
__global__ void chunk_carry_kernel(bf16* S, const float* __restrict__ A)
{
    int gid = blockIdx.x * 256 + threadIdx.x;
    if (gid >= BATCH * NHEADS * HEADDIM * DSTATE) return;
    int es = gid & (HEADDIM * DSTATE - 1);
    int h  = (gid >> 13) & (NHEADS - 1);
    int b  = gid >> 17;
    const float* Ab = A + ((size_t)b * NHEADS + h) * NCHUNK;
    float hstate = 0.f;
    size_t stride = (size_t)NHEADS * HEADDIM * DSTATE;
    bf16* p = S + ((size_t)b * NCHUNK * NHEADS + h) * (HEADDIM * DSTATE) + es;
    for (int c = 0; c < NCHUNK; ++c) {
        float sv = (float)*p;
        *p = (bf16)hstate;
        hstate = fmaf(Ab[c], hstate, sv);
        p += stride;
    }
}

// Pass 2: re-run local scan seeded with H_c; y written in-place over x.
__global__ __launch_bounds__(256) void chunk_y_kernel(
    bf16* xy,                       // [BL][DINNER]: x in, y out
    const bf16* __restrict__ zb,    // B/C in z, stride ZDIM
    const float* __restrict__ abar,
    const bf16* __restrict__ H)     // [B][NCHUNK][NHEADS][8192]
{
    __shared__ __align__(16) bf16 x_lds[QCHUNK * HEADDIM];
    __shared__ __align__(16) bf16 B_lds[QCHUNK * DSTATE];
    __shared__ __align__(16) bf16 C_lds[QCHUNK * DSTATE];
    __shared__ float a_lds[QCHUNK];
    int blk = blockIdx.x;
    int h = blk & 15;
    int c = (blk >> 4) & (NCHUNK - 1);
    int b = blk >> 10;
    int tid = threadIdx.x;
    size_t row0 = (size_t)b * LSEQ + (size_t)c * QCHUNK;
    bf16* xg = xy + row0 * DINNER + h * HEADDIM;
    const bf16* Bg = zb + row0 * ZDIM + DINNER + h * DSTATE;
    const bf16* Cg = Bg + NHEADS * DSTATE;

#pragma unroll
    for (int it = 0; it < 4; ++it) {
        int idx = it * 256 + tid;
        int r = idx >> 4, cc = (idx & 15) * 8;
        __builtin_amdgcn_global_load_lds(
            (const __attribute__((address_space(1))) void*)(xg + (size_t)r * DINNER + cc),
            (__attribute__((address_space(3))) void*)(&x_lds[idx * 8]), 16, 0, 0);
    }
#pragma unroll
    for (int it = 0; it < 2; ++it) {
        int idx = it * 256 + tid;
        int r = idx >> 3, cc = (idx & 7) * 8;
        __builtin_amdgcn_global_load_lds(
            (const __attribute__((address_space(1))) void*)(Bg + (size_t)r * ZDIM + cc),
            (__attribute__((address_space(3))) void*)(&B_lds[idx * 8]), 16, 0, 0);
        __builtin_amdgcn_global_load_lds(
            (const __attribute__((address_space(1))) void*)(Cg + (size_t)r * ZDIM + cc),
            (__attribute__((address_space(3))) void*)(&C_lds[idx * 8]), 16, 0, 0);
    }
    if (tid < QCHUNK) a_lds[tid] = abar[(row0 + tid) * NHEADS + h];
    __syncthreads();

    int sg = tid & 7, dg = tid >> 3;
    int s0 = sg * 8, d0 = dg * 4;

    const bf16* Hg = H + ((size_t)(b * NCHUNK + c) * NHEADS + h) * (HEADDIM * DSTATE);
    float hs[4][8];
#pragma unroll
    for (int i = 0; i < 4; i++) {
        bf16x8 hv = *reinterpret_cast<const bf16x8*>(&Hg[(d0 + i) * DSTATE + s0]);
#pragma unroll
        for (int j = 0; j < 8; j++) hs[i][j] = (float)hv[j];
    }

    for (int t = 0; t < QCHUNK; ++t) {
        float a = a_lds[t];
        bf16x4 xv = *reinterpret_cast<const bf16x4*>(&x_lds[t * HEADDIM + d0]);
        bf16x8 bv = *reinterpret_cast<const bf16x8*>(&B_lds[t * DSTATE + s0]);
        bf16x8 cv = *reinterpret_cast<const bf16x8*>(&C_lds[t * DSTATE + s0]);
        float xf[4], bfv[8], cfv[8];
#pragma unroll
        for (int i = 0; i < 4; i++) xf[i] = (float)xv[i];
#pragma unroll
        for (int j = 0; j < 8; j++) bfv[j] = (float)bv[j];
#pragma unroll
        for (int j = 0; j < 8; j++) cfv[j] = (float)cv[j];
        float py[4];
#pragma unroll
        for (int i = 0; i < 4; i++) {
            py[i] = 0.f;
#pragma unroll
            for (int j = 0; j < 8; j++) {
                hs[i][j] = fmaf(a, hs[i][j], xf[i] * bfv[j]);
                py[i] = fmaf(hs[i][j], cfv[j], py[i]);
            }
        }
#pragma unroll
        for (int i = 0; i < 4; i++) {
            py[i] += __shfl_xor(py[i], 1);
            py[i] += __shfl_xor(py[i], 2);
            py[i] += __shfl_xor(py[i], 4);
        }
        if (sg == 0) {
            bf16x4 o;
#pragma unroll
            for (int i = 0; i < 4; i++) o[i] = (bf16)py[i];
            *reinterpret_cast<bf16x4*>(&xg[(size_t)t * DINNER + d0]) = o;
        }
    }
}

// ---------------- gate (sigmoid) * y, RMS norm, -> bf16 (in-place over g) ----------------
__global__ __launch_bounds__(256) void gate_rms_kernel(
    const bf16* __restrict__ y,   // [BL][2048]
    bf16* g,                      // [BL][2048]: gate pre-act in, normalized y out
    const float* __restrict__ norm_w)
{
    __shared__ float red[4];
    int row = blockIdx.x, t = threadIdx.x;
    const bf16* yr = y + (size_t)row * DINNER;
    bf16* gr = g + (size_t)row * DINNER;
    int c0 = t * 8;
    bf16x8 yv8 = *reinterpret_cast<const bf16x8*>(yr + c0);
    bf16x8 gv8 = *reinterpret_cast<const bf16x8*>(gr + c0);
    float v[8];
#pragma unroll
    for (int i = 0; i < 8; i++) {
        float yf = (float)yv8[i];
        float gf = (float)gv8[i];
        v[i] = yf / (1.f + expf(-gf));
    }
    float ss = 0.f;
#pragma unroll
    for (int i = 0; i < 8; i++) ss += v[i] * v[i];
#pragma unroll
    for (int off = 32; off >= 1; off >>= 1) ss += __shfl_xor(ss, off);
    if ((t & 63) == 0) red[t >> 6] = ss;
    __syncthreads();
    ss = red[0] + red[1] + red[2] + red[3];
    float sc = rsqrtf(ss * (1.0f / DINNER) + 1.1920928955078125e-07f);
    float4 na = *reinterpret_cast<const float4*>(norm_w + c0);
    float4 nb = *reinterpret_cast<const float4*>(norm_w + c0 + 4);
    bf16x8 ov;
    ov[0] = (bf16)(v[0] * sc * na.x);
    ov[1] = (bf16)(v[1] * sc * na.y);
    ov[2] = (bf16)(v[2] * sc * na.z);
    ov[3] = (bf16)(v[3] * sc * na.w);
    ov[4] = (bf16)(v[4] * sc * nb.x);
    ov[5] = (bf16)(v[5] * sc * nb.y);
    ov[6] = (bf16)(v[6] * sc * nb.z);
    ov[7] = (bf16)(v[7] * sc * nb.w);
    *reinterpret_cast<bf16x8*>(gr + c0) = ov;
}

// ---------------- launch ----------------
extern "C" void kernel_launch(void* const* d_in, const int* in_sizes, int n_in,
                              void* d_out, int out_size, void* d_ws, size_t ws_size,
                              hipStream_t stream)
{
    const float* u      = (const float*)d_in[0];
    const float* W_in   = (const float*)d_in[1];
    const float* conv_w = (const float*)d_in[2];
    const float* conv_b = (const float*)d_in[3];
    const float* dparam = (const float*)d_in[4];
    const float* W_gate = (const float*)d_in[5];
    const float* norm_w = (const float*)d_in[6];
    const float* W_out  = (const float*)d_in[7];
    float* out = (float*)d_out;

    char* ws = (char*)d_ws;
    size_t off = 0;
    auto alloc = [&](size_t bytes) {
        void* p = ws + off;
        off += (bytes + 255) & ~(size_t)255;
        return p;
    };
    // total ws use: ~170 MB
    bf16*  u_bf  = (bf16*) alloc((size_t)BLROWS * DMODEL * 2);   // 16.8 MB
    bf16*  Wt_in = (bf16*) alloc((size_t)NPAD_IN * DMODEL * 2);  // 8.7 MB
    bf16*  Wt_g  = (bf16*) alloc((size_t)DINNER * DMODEL * 2);   // 4.2 MB
    bf16*  Wt_o  = (bf16*) alloc((size_t)DMODEL * DINNER * 2);   // 4.2 MB
    bf16*  z     = (bf16*) alloc((size_t)BLROWS * ZDIM * 2);     // 67.4 MB
    bf16*  g     = (bf16*) alloc((size_t)BLROWS * DINNER * 2);   // 33.6 MB (yn in-place)
    float* dt    = (float*)alloc((size_t)BLROWS * NHEADS * 4);   // 0.5 MB
    float* abar  = (float*)alloc((size_t)BLROWS * NHEADS * 4);   // 0.5 MB
    bf16*  S     = (bf16*) alloc((size_t)BATCH * NCHUNK * NHEADS * HEADDIM * DSTATE * 2); // 33.6 MB
    float* Adec  = (float*)alloc((size_t)BATCH * NHEADS * NCHUNK * 4);                    // 8 KB
    // x/y live in d_out (33.5 MB, fully overwritten by the final GEMM)
    bf16* xy = (bf16*)d_out;
    (void)ws_size; (void)in_sizes; (void)n_in; (void)out_size;

    dim3 tb(32, 8);
    cvt_bf16_kernel<<<(BLROWS * DMODEL / 4 + 255) / 256, 256, 0, stream>>>(u, u_bf, BLROWS * DMODEL);
    transpose_cvt_kernel<<<dim3(NPAD_IN / 32, DMODEL / 32), tb, 0, stream>>>(W_in, Wt_in, DMODEL, ZDIM, NPAD_IN);
    transpose_cvt_kernel<<<dim3(DINNER / 32, DMODEL / 32), tb, 0, stream>>>(W_gate, Wt_g, DMODEL, DINNER, DINNER);
    transpose_cvt_kernel<<<dim3(DMODEL / 32, DINNER / 32), tb, 0, stream>>>(W_out, Wt_o, DINNER, DMODEL, DMODEL);

    // z = u @ W_in (bf16 out + f32 dt sidecar)   M=8192, K=1024, N=4112 (pad 4224)
    gemm_bf16_kernel<true, true><<<dim3(NPAD_IN / 128, BLROWS / 128), 256, 0, stream>>>(
        u_bf, Wt_in, z, dt, DMODEL, ZDIM, ZDIM);
    // g = u @ W_gate (bf16 out)                  N=2048
    gemm_bf16_kernel<true, false><<<dim3(DINNER / 128, BLROWS / 128), 256, 0, stream>>>(
        u_bf, Wt_g, g, nullptr, DMODEL, DINNER, DINNER);

    conv_silu_kernel<<<(BLROWS * DINNER + 255) / 256, 256, 0, stream>>>(z, conv_w, conv_b, xy);
    abar_kernel<<<(BLROWS * NHEADS + 255) / 256, 256, 0, stream>>>(dt, dparam, abar);

    // chunked scan: S_c + A_c per chunk -> inter-chunk carry -> seeded local scan
    chunk_state_kernel<<<BATCH * NCHUNK * NHEADS, 256, 0, stream>>>(xy, z, abar, S, Adec);
    chunk_carry_kernel<<<(BATCH * NHEADS * HEADDIM * DSTATE) / 256, 256, 0, stream>>>(S, Adec);
    chunk_y_kernel<<<BATCH * NCHUNK * NHEADS, 256, 0, stream>>>(xy, z, abar, S);

    gate_rms_kernel<<<BLROWS, 256, 0, stream>>>(xy, g, norm_w);

    // out = yn @ W_out (f32 out)   M=8192, K=2048, N=1024 — overwrites xy region
    gemm_bf16_kernel<false, false><<<dim3(DMODEL / 128, BLROWS / 128), 256, 0, stream>>>(
        g, Wt_o, out, nullptr, DINNER, DMODEL, DMODEL);
}

// Round 4
// 397.549 us; speedup vs baseline: 4.0782x; 1.2835x over previous
//
#include <hip/hip_runtime.h>

#define BATCH   2
#define LSEQ    4096
#define DMODEL  1024
#define DINNER  2048
#define NHEADS  16
#define DSTATE  64
#define HEADDIM 128
#define ZDIM    4112
#define BLROWS  (BATCH*LSEQ)   // 8192
#define NPAD_IN 4224           // 4112 padded to 33*128
#define QCHUNK  64
#define NCHUNK  (LSEQ/QCHUNK)  // 64

#define AS1 __attribute__((address_space(1)))
#define AS3 __attribute__((address_space(3)))

typedef __bf16 bf16;
typedef __bf16 bf16x8 __attribute__((ext_vector_type(8)));
typedef __bf16 bf16x4 __attribute__((ext_vector_type(4)));
typedef float  f32x4  __attribute__((ext_vector_type(4)));

// ---------------- fp32 -> bf16 convert (vectorized) ----------------
__global__ void cvt_bf16_kernel(const float* __restrict__ in, bf16* __restrict__ out, int n)
{
    int i = (blockIdx.x * 256 + threadIdx.x) * 4;
    if (i >= n) return;
    float4 v = *reinterpret_cast<const float4*>(in + i);
    bf16x4 o;
    o[0] = (bf16)v.x; o[1] = (bf16)v.y; o[2] = (bf16)v.z; o[3] = (bf16)v.w;
    *reinterpret_cast<bf16x4*>(out + i) = o;
}

// ---------------- transpose + convert: src[R][C] f32 -> dst[Cpad][R] bf16 ----------------
__global__ void transpose_cvt_kernel(const float* __restrict__ src, bf16* __restrict__ dst,
                                     int R, int C, int Cpad)
{
    __shared__ float tile[32][33];
    int tx = threadIdx.x;   // 0..31
    int ty = threadIdx.y;   // 0..7
    int c0 = blockIdx.x * 32;
    int r0 = blockIdx.y * 32;
#pragma unroll
    for (int q = 0; q < 4; q++) {
        int r = r0 + ty + q * 8;
        int c = c0 + tx;
        float v = 0.f;
        if (r < R && c < C) v = src[(size_t)r * C + c];
        tile[ty + q * 8][tx] = v;
    }
    __syncthreads();
#pragma unroll
    for (int q = 0; q < 4; q++) {
        int oc = c0 + ty + q * 8;   // output row (= original col)
        int orr = r0 + tx;          // output col (= original row)
        if (oc < Cpad && orr < R)
            dst[(size_t)oc * R + orr] = (bf16)tile[tx][ty + q * 8];
    }
}

// ---------------- bf16 MFMA GEMM: C[M][Ns] = A[M][K] * Bt[Npad][K]^T ----------------
template<bool BF16OUT, bool HASDT>
__global__ __launch_bounds__(256) void gemm_bf16_kernel(
    const bf16* __restrict__ A,   // [M][K] row-major
    const bf16* __restrict__ Bt,  // [Npad][K] row-major (B transposed)
    void* __restrict__ Cout,      // [M][Ns]
    float* __restrict__ dtout,    // [M][16] f32 sidecar (HASDT only)
    int K, int Ns, int Nstore)
{
    __shared__ __align__(16) bf16 As[128 * 32];
    __shared__ __align__(16) bf16 Bs[128 * 32];
    const int t = threadIdx.x;
    const int bm = blockIdx.y, bn = blockIdx.x;
    const int w = t >> 6, lane = t & 63;
    const int wm = (w >> 1) * 64, wn = (w & 1) * 64;
    const int lm = lane & 15, lk = (lane >> 4) * 8;

    const bf16* Ab = A + (size_t)(bm * 128) * K;
    const bf16* Bb = Bt + (size_t)(bn * 128) * K;

    const int e0 = t * 8;
    const int r0s = e0 >> 5, k0s = e0 & 31;
    const int e1 = e0 + 2048;
    const int r1s = e1 >> 5, k1s = e1 & 31;

    f32x4 acc[4][4];
#pragma unroll
    for (int i = 0; i < 4; i++)
#pragma unroll
        for (int j = 0; j < 4; j++) acc[i][j] = (f32x4){0.f, 0.f, 0.f, 0.f};

    for (int k0 = 0; k0 < K; k0 += 32) {
        __builtin_amdgcn_global_load_lds(
            (const AS1 void*)(Ab + (size_t)r0s * K + k0 + k0s),
            (AS3 void*)(&As[e0]), 16, 0, 0);
        __builtin_amdgcn_global_load_lds(
            (const AS1 void*)(Ab + (size_t)r1s * K + k0 + k1s),
            (AS3 void*)(&As[e1]), 16, 0, 0);
        __builtin_amdgcn_global_load_lds(
            (const AS1 void*)(Bb + (size_t)r0s * K + k0 + k0s),
            (AS3 void*)(&Bs[e0]), 16, 0, 0);
        __builtin_amdgcn_global_load_lds(
            (const AS1 void*)(Bb + (size_t)r1s * K + k0 + k1s),
            (AS3 void*)(&Bs[e1]), 16, 0, 0);
        __syncthreads();

        bf16x8 af[4], bfr[4];
#pragma unroll
        for (int i = 0; i < 4; i++)
            af[i] = *reinterpret_cast<const bf16x8*>(&As[(wm + i * 16 + lm) * 32 + lk]);
#pragma unroll
        for (int j = 0; j < 4; j++)
            bfr[j] = *reinterpret_cast<const bf16x8*>(&Bs[(wn + j * 16 + lm) * 32 + lk]);
#pragma unroll
        for (int i = 0; i < 4; i++)
#pragma unroll
            for (int j = 0; j < 4; j++)
                acc[i][j] = __builtin_amdgcn_mfma_f32_16x16x32_bf16(af[i], bfr[j], acc[i][j], 0, 0, 0);
        __syncthreads();
    }

    const int rrow = (lane >> 4) * 4;
    const int ccol = lane & 15;
#pragma unroll
    for (int i = 0; i < 4; i++) {
#pragma unroll
        for (int j = 0; j < 4; j++) {
            int col = bn * 128 + wn + j * 16 + ccol;
            if (col < Nstore) {
#pragma unroll
                for (int r = 0; r < 4; r++) {
                    int row = bm * 128 + wm + i * 16 + rrow + r;
                    float v = acc[i][j][r];
                    if constexpr (BF16OUT)
                        ((bf16*)Cout)[(size_t)row * Ns + col] = (bf16)v;
                    else
                        ((float*)Cout)[(size_t)row * Ns + col] = v;
                    if constexpr (HASDT) {
                        if (col >= DINNER + 2048)
                            dtout[(size_t)row * NHEADS + (col - (DINNER + 2048))] = v;
                    }
                }
            }
        }
    }
}

// ---------------- causal depthwise conv (D_CONV=4) + SiLU ----------------
__global__ void conv_silu_kernel(const bf16* __restrict__ z, const float* __restrict__ conv_w,
                                 const float* __restrict__ conv_b, bf16* __restrict__ x)
{
    int gid = blockIdx.x * 256 + threadIdx.x;
    if (gid >= BLROWS * DINNER) return;
    int c = gid & (DINNER - 1);
    int bl = gid >> 11;
    int l = bl & (LSEQ - 1);
    float4 w4 = *reinterpret_cast<const float4*>(conv_w + (size_t)c * 4);
    float acc = conv_b[c];
    if (l - 3 >= 0) acc += (float)z[(size_t)(bl - 3) * ZDIM + c] * w4.x;
    if (l - 2 >= 0) acc += (float)z[(size_t)(bl - 2) * ZDIM + c] * w4.y;
    if (l - 1 >= 0) acc += (float)z[(size_t)(bl - 1) * ZDIM + c] * w4.z;
    acc += (float)z[(size_t)bl * ZDIM + c] * w4.w;
    x[(size_t)gid] = (bf16)(acc / (1.f + expf(-acc)));   // silu
}

// ---------------- la = log(a_bar) = -softplus(dt+dp)*|dt| ----------------
__global__ void la_kernel(const float* __restrict__ dt_in, const float* __restrict__ dparam,
                          float* __restrict__ la)
{
    int i = blockIdx.x * 256 + threadIdx.x;
    if (i >= BLROWS * NHEADS) return;
    int h = i & (NHEADS - 1);
    float dt = dt_in[i];
    float v = dt + dparam[h];
    float sp = (v > 20.f) ? v : log1pf(expf(v));
    la[i] = -sp * fabsf(dt);
}

// ================= chunked scan, SSD matmul form =================
// Pass 1: S_c[d][s] = sum_t x[t,d] * (w_t B[t,s]),  w_t = exp(Ls_Q - Ls_t)
__global__ __launch_bounds__(256) void chunk_state_kernel(
    const bf16* __restrict__ x,    // [BL][DINNER]
    const bf16* __restrict__ zb,   // B at col DINNER+h*64, stride ZDIM
    const float* __restrict__ la,  // [BL][16] log a
    bf16* __restrict__ S,          // [B][NCHUNK][NHEADS][128*64]
    float* __restrict__ Adec)      // [B][NHEADS][NCHUNK] = exp(Ls_Q)
{
    __shared__ __align__(16) bf16 xt[HEADDIM * QCHUNK]; // [d][t] swizzled
    __shared__ __align__(16) bf16 bw[DSTATE * QCHUNK];  // [s][t] swizzled, weighted
    __shared__ float Ls[QCHUNK];
    const int blk = blockIdx.x;
    const int h = blk & 15, c = (blk >> 4) & 63, b = blk >> 10;
    const int tid = threadIdx.x, lane = tid & 63, w = tid >> 6;
    const size_t row0 = (size_t)b * LSEQ + (size_t)c * QCHUNK;
    const bf16* xg = x + row0 * DINNER + h * HEADDIM;
    const bf16* Bg = zb + row0 * ZDIM + DINNER + h * DSTATE;

    const int t = tid >> 2, dseg = (tid & 3) * 32, sseg = (tid & 3) * 16;
    bf16x8 xr[4], br[2];
#pragma unroll
    for (int q = 0; q < 4; q++)
        xr[q] = *reinterpret_cast<const bf16x8*>(xg + (size_t)t * DINNER + dseg + q * 8);
#pragma unroll
    for (int q = 0; q < 2; q++)
        br[q] = *reinterpret_cast<const bf16x8*>(Bg + (size_t)t * ZDIM + sseg + q * 8);

    if (w == 0) {
        float v = la[(row0 + lane) * NHEADS + h];
#pragma unroll
        for (int off = 1; off < 64; off <<= 1) { float o = __shfl_up(v, off); if (lane >= off) v += o; }
        Ls[lane] = v;
        if (lane == 63) Adec[((size_t)b * NHEADS + h) * NCHUNK + c] = __expf(v);
    }
    __syncthreads();
    const float wt = __expf(Ls[QCHUNK - 1] - Ls[t]);
    const int tb = t >> 3, ti = t & 7;
#pragma unroll
    for (int q = 0; q < 4; q++)
#pragma unroll
        for (int j = 0; j < 8; j++) {
            int d = dseg + q * 8 + j;
            xt[d * 64 + ((tb ^ (d & 7)) << 3) + ti] = xr[q][j];
        }
#pragma unroll
    for (int q = 0; q < 2; q++)
#pragma unroll
        for (int j = 0; j < 8; j++) {
            int s = sseg + q * 8 + j;
            bw[s * 64 + ((tb ^ (s & 7)) << 3) + ti] = (bf16)((float)br[q][j] * wt);
        }
    __syncthreads();

    f32x4 acc[2][4];
#pragma unroll
    for (int i = 0; i < 2; i++)
#pragma unroll
        for (int j = 0; j < 4; j++) acc[i][j] = (f32x4){0.f, 0.f, 0.f, 0.f};
#pragma unroll
    for (int kk = 0; kk < 2; kk++) {
        const int kb = kk * 4 + (lane >> 4);
        bf16x8 af[2], bf2[4];
#pragma unroll
        for (int i = 0; i < 2; i++) {
            int d = w * 32 + i * 16 + (lane & 15);
            af[i] = *reinterpret_cast<const bf16x8*>(&xt[d * 64 + ((kb ^ (d & 7)) << 3)]);
        }
#pragma unroll
        for (int j = 0; j < 4; j++) {
            int s = j * 16 + (lane & 15);
            bf2[j] = *reinterpret_cast<const bf16x8*>(&bw[s * 64 + ((kb ^ (s & 7)) << 3)]);
        }
#pragma unroll
        for (int i = 0; i < 2; i++)
#pragma unroll
            for (int j = 0; j < 4; j++)
                acc[i][j] = __builtin_amdgcn_mfma_f32_16x16x32_bf16(af[i], bf2[j], acc[i][j], 0, 0, 0);
    }
    bf16* Sg = S + ((size_t)(b * NCHUNK + c) * NHEADS + h) * (HEADDIM * DSTATE);
    const int rr = (lane >> 4) * 4, ccol = lane & 15;
#pragma unroll
    for (int i = 0; i < 2; i++)
#pragma unroll
        for (int j = 0; j < 4; j++)
#pragma unroll
            for (int r = 0; r < 4; r++)
                Sg[(w * 32 + i * 16 + rr + r) * 64 + j * 16 + ccol] = (bf16)acc[i][j][r];
}

// Pass 1b: inter-chunk carry, in-place: S_c -> H_c (state at chunk START).
__global__ void chunk_carry_kernel(bf16* S, const float* __restrict__ A)
{
    int gid = blockIdx.x * 256 + threadIdx.x;
    if (gid >= BATCH * NHEADS * HEADDIM * DSTATE) return;
    int es = gid & (HEADDIM * DSTATE - 1);
    int h  = (gid >> 13) & (NHEADS - 1);
    int b  = gid >> 17;
    const float* Ab = A + ((size_t)b * NHEADS + h) * NCHUNK;
    float hstate = 0.f;
    size_t stride = (size_t)NHEADS * HEADDIM * DSTATE;
    bf16* p = S + ((size_t)b * NCHUNK * NHEADS + h) * (HEADDIM * DSTATE) + es;
    for (int c = 0; c < NCHUNK; ++c) {
        float sv = (float)*p;
        *p = (bf16)hstate;
        hstate = fmaf(Ab[c], hstate, sv);
        p += stride;
    }
}

// Pass 2: Y^T[d][t] = [Xt | H] @ [MG | P.C]^T  (K = 64 t' + 64 s), in-place over X.
__global__ __launch_bounds__(256) void chunk_y_kernel(
    bf16* xy,                       // [BL][DINNER]: x in, y out (same storage)
    const bf16* __restrict__ zb,    // B/C in z, stride ZDIM
    const float* __restrict__ la,   // [BL][16] log a
    const bf16* __restrict__ H)     // [B][NCHUNK][NHEADS][128*64] chunk-start state
{
    __shared__ __align__(16) bf16 bc[QCHUNK * 128];    // B[0..4095] | C[4096..8191], later MG[64][128]
    __shared__ __align__(16) bf16 xt[HEADDIM * QCHUNK];
    __shared__ __align__(16) bf16 hl[HEADDIM * DSTATE];
    __shared__ float Ls[QCHUNK];
    const int blk = blockIdx.x;
    const int h = blk & 15, c = (blk >> 4) & 63, b = blk >> 10;
    const int tid = threadIdx.x, lane = tid & 63, w = tid >> 6;
    const size_t row0 = (size_t)b * LSEQ + (size_t)c * QCHUNK;
    bf16* xg = xy + row0 * DINNER + h * HEADDIM;
    const bf16* Bg = zb + row0 * ZDIM + DINNER + h * DSTATE;
    const bf16* Cg = Bg + NHEADS * DSTATE;
    const bf16* Hg = H + ((size_t)(b * NCHUNK + c) * NHEADS + h) * (HEADDIM * DSTATE);

    // stage B, C (pre-swizzled source -> linear LDS dest)
#pragma unroll
    for (int it = 0; it < 2; it++) {
        int idx = it * 256 + tid;
        int row = idx >> 3, p = idx & 7;
        int sc = (p ^ (row & 7)) << 3;
        __builtin_amdgcn_global_load_lds((const AS1 void*)(Bg + (size_t)row * ZDIM + sc),
                                         (AS3 void*)(&bc[idx * 8]), 16, 0, 0);
        __builtin_amdgcn_global_load_lds((const AS1 void*)(Cg + (size_t)row * ZDIM + sc),
                                         (AS3 void*)(&bc[4096 + idx * 8]), 16, 0, 0);
    }
    // stage H
#pragma unroll
    for (int it = 0; it < 4; it++) {
        int idx = it * 256 + tid;
        int d = idx >> 3, p = idx & 7;
        __builtin_amdgcn_global_load_lds((const AS1 void*)(Hg + d * 64 + ((p ^ (d & 7)) << 3)),
                                         (AS3 void*)(&hl[idx * 8]), 16, 0, 0);
    }
    // X -> regs (for transpose staging)
    const int t = tid >> 2, dseg = (tid & 3) * 32, sseg = (tid & 3) * 16;
    bf16x8 xr[4];
#pragma unroll
    for (int q = 0; q < 4; q++)
        xr[q] = *reinterpret_cast<const bf16x8*>(xg + (size_t)t * DINNER + dseg + q * 8);
    // log-decay cumsum
    if (w == 0) {
        float v = la[(row0 + lane) * NHEADS + h];
#pragma unroll
        for (int off = 1; off < 64; off <<= 1) { float o = __shfl_up(v, off); if (lane >= off) v += o; }
        Ls[lane] = v;
    }
    __syncthreads();

    // write transposed X
    const int tb = t >> 3, ti = t & 7;
#pragma unroll
    for (int q = 0; q < 4; q++)
#pragma unroll
        for (int j = 0; j < 8; j++) {
            int d = dseg + q * 8 + j;
            xt[d * 64 + ((tb ^ (d & 7)) << 3) + ti] = xr[q][j];
        }

    // MFMA1: G[t][t'] = sum_s C[t,s] B[t',s]; wave w owns t-rows w*16..+15
    f32x4 g[4];
#pragma unroll
    for (int j = 0; j < 4; j++) g[j] = (f32x4){0.f, 0.f, 0.f, 0.f};
#pragma unroll
    for (int kk = 0; kk < 2; kk++) {
        const int kb = kk * 4 + (lane >> 4);
        const int tA = w * 16 + (lane & 15);
        bf16x8 ca = *reinterpret_cast<const bf16x8*>(&bc[4096 + tA * 64 + ((kb ^ (tA & 7)) << 3)]);
#pragma unroll
        for (int j = 0; j < 4; j++) {
            int tB = j * 16 + (lane & 15);
            bf16x8 bb = *reinterpret_cast<const bf16x8*>(&bc[tB * 64 + ((kb ^ (tB & 7)) << 3)]);
            g[j] = __builtin_amdgcn_mfma_f32_16x16x32_bf16(ca, bb, g[j], 0, 0, 0);
        }
    }
    // read C (for P.C) before bc is overwritten
    bf16x8 cr[2];
#pragma unroll
    for (int q = 0; q < 2; q++) {
        int sblk = (sseg >> 3) + q;
        cr[q] = *reinterpret_cast<const bf16x8*>(&bc[4096 + t * 64 + ((sblk ^ (t & 7)) << 3)]);
    }
    const float pscale = __expf(Ls[t]);
    __syncthreads();   // all B/C reads complete

    // build MG (left half) from G
    {
        const int tpbase = lane & 15;
        const int tgbase = w * 16 + (lane >> 4) * 4;
        float lst[4];
#pragma unroll
        for (int r = 0; r < 4; r++) lst[r] = Ls[tgbase + r];
#pragma unroll
        for (int j = 0; j < 4; j++) {
            int tp = j * 16 + tpbase;
            float lstp = Ls[tp];
#pragma unroll
            for (int r = 0; r < 4; r++) {
                int tg = tgbase + r;
                float mg = (tp <= tg) ? g[j][r] * __expf(lst[r] - lstp) : 0.f;
                bc[tg * 128 + (((tp >> 3) ^ (tg & 7)) << 3) + (tp & 7)] = (bf16)mg;
            }
        }
    }
    // build P.C (right half)
#pragma unroll
    for (int q = 0; q < 2; q++) {
        int sblk = (sseg >> 3) + q;
        bf16x8 o;
#pragma unroll
        for (int j = 0; j < 8; j++) o[j] = (bf16)((float)cr[q][j] * pscale);
        *reinterpret_cast<bf16x8*>(&bc[t * 128 + ((8 + (sblk ^ (t & 7))) << 3)]) = o;
    }
    __syncthreads();   // MG ready

    // MFMA2: Yt[d][t] over K=128; wave w owns d-rows w*32..+31
    f32x4 acc[2][4];
#pragma unroll
    for (int i = 0; i < 2; i++)
#pragma unroll
        for (int j = 0; j < 4; j++) acc[i][j] = (f32x4){0.f, 0.f, 0.f, 0.f};
#pragma unroll
    for (int kk = 0; kk < 4; kk++) {
        const int kb = kk * 4 + (lane >> 4);   // 0..15
        bf16x8 af[2];
#pragma unroll
        for (int i = 0; i < 2; i++) {
            int d = w * 32 + i * 16 + (lane & 15);
            if (kk < 2)
                af[i] = *reinterpret_cast<const bf16x8*>(&xt[d * 64 + ((kb ^ (d & 7)) << 3)]);
            else
                af[i] = *reinterpret_cast<const bf16x8*>(&hl[d * 64 + (((kb - 8) ^ (d & 7)) << 3)]);
        }
#pragma unroll
        for (int j = 0; j < 4; j++) {
            int tt = j * 16 + (lane & 15);
            bf16x8 b2 = *reinterpret_cast<const bf16x8*>(&bc[tt * 128 + ((kb ^ (tt & 7)) << 3)]);
#pragma unroll
            for (int i = 0; i < 2; i++)
                acc[i][j] = __builtin_amdgcn_mfma_f32_16x16x32_bf16(af[i], b2, acc[i][j], 0, 0, 0);
        }
    }
    // store Y (in place over X): lane holds col t, 4 consecutive d
#pragma unroll
    for (int i = 0; i < 2; i++)
#pragma unroll
        for (int j = 0; j < 4; j++) {
            int d0 = w * 32 + i * 16 + (lane >> 4) * 4;
            int tt = j * 16 + (lane & 15);
            bf16x4 o;
#pragma unroll
            for (int r = 0; r < 4; r++) o[r] = (bf16)acc[i][j][r];
            *reinterpret_cast<bf16x4*>(xg + (size_t)tt * DINNER + d0) = o;
        }
}

// ---------------- gate (sigmoid) * y, RMS norm, -> bf16 (in-place over g) ----------------
__global__ __launch_bounds__(256) void gate_rms_kernel(
    const bf16* __restrict__ y,   // [BL][2048]
    bf16* g,                      // [BL][2048]: gate pre-act in, normalized y out
    const float* __restrict__ norm_w)
{
    __shared__ float red[4];
    int row = blockIdx.x, t = threadIdx.x;
    const bf16* yr = y + (size_t)row * DINNER;
    bf16* gr = g + (size_t)row * DINNER;
    int c0 = t * 8;
    bf16x8 yv8 = *reinterpret_cast<const bf16x8*>(yr + c0);
    bf16x8 gv8 = *reinterpret_cast<const bf16x8*>(gr + c0);
    float v[8];
#pragma unroll
    for (int i = 0; i < 8; i++) {
        float yf = (float)yv8[i];
        float gf = (float)gv8[i];
        v[i] = yf / (1.f + expf(-gf));
    }
    float ss = 0.f;
#pragma unroll
    for (int i = 0; i < 8; i++) ss += v[i] * v[i];
#pragma unroll
    for (int off = 32; off >= 1; off >>= 1) ss += __shfl_xor(ss, off);
    if ((t & 63) == 0) red[t >> 6] = ss;
    __syncthreads();
    ss = red[0] + red[1] + red[2] + red[3];
    float sc = rsqrtf(ss * (1.0f / DINNER) + 1.1920928955078125e-07f);
    float4 na = *reinterpret_cast<const float4*>(norm_w + c0);
    float4 nb = *reinterpret_cast<const float4*>(norm_w + c0 + 4);
    bf16x8 ov;
    ov[0] = (bf16)(v[0] * sc * na.x);
    ov[1] = (bf16)(v[1] * sc * na.y);
    ov[2] = (bf16)(v[2] * sc * na.z);
    ov[3] = (bf16)(v[3] * sc * na.w);
    ov[4] = (bf16)(v[4] * sc * nb.x);
    ov[5] = (bf16)(v[5] * sc * nb.y);
    ov[6] = (bf16)(v[6] * sc * nb.z);
    ov[7] = (bf16)(v[7] * sc * nb.w);
    *reinterpret_cast<bf16x8*>(gr + c0) = ov;
}

// ---------------- launch ----------------
extern "C" void kernel_launch(void* const* d_in, const int* in_sizes, int n_in,
                              void* d_out, int out_size, void* d_ws, size_t ws_size,
                              hipStream_t stream)
{
    const float* u      = (const float*)d_in[0];
    const float* W_in   = (const float*)d_in[1];
    const float* conv_w = (const float*)d_in[2];
    const float* conv_b = (const float*)d_in[3];
    const float* dparam = (const float*)d_in[4];
    const float* W_gate = (const float*)d_in[5];
    const float* norm_w = (const float*)d_in[6];
    const float* W_out  = (const float*)d_in[7];
    float* out = (float*)d_out;

    char* ws = (char*)d_ws;
    size_t off = 0;
    auto alloc = [&](size_t bytes) {
        void* p = ws + off;
        off += (bytes + 255) & ~(size_t)255;
        return p;
    };
    // total ws use: ~170 MB
    bf16*  u_bf  = (bf16*) alloc((size_t)BLROWS * DMODEL * 2);   // 16.8 MB
    bf16*  Wt_in = (bf16*) alloc((size_t)NPAD_IN * DMODEL * 2);  // 8.7 MB
    bf16*  Wt_g  = (bf16*) alloc((size_t)DINNER * DMODEL * 2);   // 4.2 MB
    bf16*  Wt_o  = (bf16*) alloc((size_t)DMODEL * DINNER * 2);   // 4.2 MB
    bf16*  z     = (bf16*) alloc((size_t)BLROWS * ZDIM * 2);     // 67.4 MB
    bf16*  g     = (bf16*) alloc((size_t)BLROWS * DINNER * 2);   // 33.6 MB (yn in-place)
    float* dt    = (float*)alloc((size_t)BLROWS * NHEADS * 4);   // 0.5 MB
    float* lab   = (float*)alloc((size_t)BLROWS * NHEADS * 4);   // 0.5 MB (log a)
    bf16*  S     = (bf16*) alloc((size_t)BATCH * NCHUNK * NHEADS * HEADDIM * DSTATE * 2); // 33.6 MB
    float* Adec  = (float*)alloc((size_t)BATCH * NHEADS * NCHUNK * 4);                    // 8 KB
    // x/y live in d_out (33.5 MB, fully overwritten by the final GEMM)
    bf16* xy = (bf16*)d_out;
    (void)ws_size; (void)in_sizes; (void)n_in; (void)out_size;

    dim3 tb(32, 8);
    cvt_bf16_kernel<<<(BLROWS * DMODEL / 4 + 255) / 256, 256, 0, stream>>>(u, u_bf, BLROWS * DMODEL);
    transpose_cvt_kernel<<<dim3(NPAD_IN / 32, DMODEL / 32), tb, 0, stream>>>(W_in, Wt_in, DMODEL, ZDIM, NPAD_IN);
    transpose_cvt_kernel<<<dim3(DINNER / 32, DMODEL / 32), tb, 0, stream>>>(W_gate, Wt_g, DMODEL, DINNER, DINNER);
    transpose_cvt_kernel<<<dim3(DMODEL / 32, DINNER / 32), tb, 0, stream>>>(W_out, Wt_o, DINNER, DMODEL, DMODEL);

    // z = u @ W_in (bf16 out + f32 dt sidecar)   M=8192, K=1024, N=4112 (pad 4224)
    gemm_bf16_kernel<true, true><<<dim3(NPAD_IN / 128, BLROWS / 128), 256, 0, stream>>>(
        u_bf, Wt_in, z, dt, DMODEL, ZDIM, ZDIM);
    // g = u @ W_gate (bf16 out)                  N=2048
    gemm_bf16_kernel<true, false><<<dim3(DINNER / 128, BLROWS / 128), 256, 0, stream>>>(
        u_bf, Wt_g, g, nullptr, DMODEL, DINNER, DINNER);

    conv_silu_kernel<<<(BLROWS * DINNER + 255) / 256, 256, 0, stream>>>(z, conv_w, conv_b, xy);
    la_kernel<<<(BLROWS * NHEADS + 255) / 256, 256, 0, stream>>>(dt, dparam, lab);

    // chunked scan (SSD matmul form)
    chunk_state_kernel<<<BATCH * NCHUNK * NHEADS, 256, 0, stream>>>(xy, z, lab, S, Adec);
    chunk_carry_kernel<<<(BATCH * NHEADS * HEADDIM * DSTATE) / 256, 256, 0, stream>>>(S, Adec);
    chunk_y_kernel<<<BATCH * NCHUNK * NHEADS, 256, 0, stream>>>(xy, z, lab, S);

    gate_rms_kernel<<<BLROWS, 256, 0, stream>>>(xy, g, norm_w);

    // out = yn @ W_out (f32 out)   M=8192, K=2048, N=1024 — overwrites xy region
    gemm_bf16_kernel<false, false><<<dim3(DMODEL / 128, BLROWS / 128), 256, 0, stream>>>(
        g, Wt_o, out, nullptr, DINNER, DMODEL, DMODEL);
}

// Round 5
// 377.933 us; speedup vs baseline: 4.2899x; 1.0519x over previous
//
#include <hip/hip_runtime.h>

#define BATCH   2
#define LSEQ    4096
#define DMODEL  1024
#define DINNER  2048
#define NHEADS  16
#define DSTATE  64
#define HEADDIM 128
#define ZDIM    4112
#define BLROWS  (BATCH*LSEQ)   // 8192
#define NFUSE   6400           // 4112(z)+112(pad)+2048(g)+128(pad), 25*256
#define QCHUNK  64
#define NCHUNK  (LSEQ/QCHUNK)  // 64

#define AS1 __attribute__((address_space(1)))
#define AS3 __attribute__((address_space(3)))

typedef __bf16 bf16;
typedef __bf16 bf16x8 __attribute__((ext_vector_type(8)));
typedef __bf16 bf16x4 __attribute__((ext_vector_type(4)));
typedef float  f32x4  __attribute__((ext_vector_type(4)));

// ---------------- fp32 -> bf16 convert (vectorized) ----------------
__global__ void cvt_bf16_kernel(const float* __restrict__ in, bf16* __restrict__ out, int n)
{
    int i = (blockIdx.x * 256 + threadIdx.x) * 4;
    if (i >= n) return;
    float4 v = *reinterpret_cast<const float4*>(in + i);
    bf16x4 o;
    o[0] = (bf16)v.x; o[1] = (bf16)v.y; o[2] = (bf16)v.z; o[3] = (bf16)v.w;
    *reinterpret_cast<bf16x4*>(out + i) = o;
}

// ---------------- transpose + convert: src[R][C] f32 -> dst[Cpad][R] bf16 ----------------
__global__ void transpose_cvt_kernel(const float* __restrict__ src, bf16* __restrict__ dst,
                                     int R, int C, int Cpad)
{
    __shared__ float tile[32][33];
    int tx = threadIdx.x;   // 0..31
    int ty = threadIdx.y;   // 0..7
    int c0 = blockIdx.x * 32;
    int r0 = blockIdx.y * 32;
#pragma unroll
    for (int q = 0; q < 4; q++) {
        int r = r0 + ty + q * 8;
        int c = c0 + tx;
        float v = 0.f;
        if (r < R && c < C) v = src[(size_t)r * C + c];
        tile[ty + q * 8][tx] = v;
    }
    __syncthreads();
#pragma unroll
    for (int q = 0; q < 4; q++) {
        int oc = c0 + ty + q * 8;   // output row (= original col)
        int orr = r0 + tx;          // output col (= original row)
        if (oc < Cpad && orr < R)
            dst[(size_t)oc * R + orr] = (bf16)tile[tx][ty + q * 8];
    }
}

// ======= fused z|g GEMM: 256x256 tile, BK=64, 8 waves, T2 swizzle + counted vmcnt =======
// A [8192][1024] bf16, Bt = Wt_fused [6400][1024] bf16.
// cols 0..4111 -> z (bf16, stride ZDIM) + f32 dt sidecar for 4096..4111
// cols 4224..6271 -> g (bf16, stride DINNER); others dropped.
__global__ __launch_bounds__(512, 2) void gemm_fused_kernel(
    const bf16* __restrict__ A, const bf16* __restrict__ Bt,
    bf16* __restrict__ z, bf16* __restrict__ g, float* __restrict__ dtout)
{
    __shared__ __align__(16) bf16 sA[2][256 * 64];  // 64 KB
    __shared__ __align__(16) bf16 sB[2][256 * 64];  // 64 KB
    const int tid = threadIdx.x;
    const int lane = tid & 63, wid = tid >> 6;
    const int wm = (wid >> 2) * 128, wn = (wid & 3) * 64;
    const int lm = lane & 15, lkc = lane >> 4;  // chunk index 0..3

    // bijective XCD swizzle: nwg=800, 800%8==0
    int bid = blockIdx.x;
    int wgid = (bid & 7) * 100 + (bid >> 3);
    const int bm = wgid / 25, bn = wgid % 25;

    const bf16* Abase = A + (size_t)(bm * 256) * 1024;
    const bf16* Bbase = Bt + (size_t)(bn * 256) * 1024;

#define STAGE_F(bufidx, kt) do {                                                          \
    const bf16* Agt = Abase + (size_t)(kt) * 64;                                          \
    const bf16* Bgt = Bbase + (size_t)(kt) * 64;                                          \
    _Pragma("unroll") for (int it = 0; it < 4; ++it) {                                    \
        int idx = it * 512 + tid; int r = idx >> 3, p = idx & 7;                          \
        __builtin_amdgcn_global_load_lds(                                                 \
            (const AS1 void*)(Agt + (size_t)r * 1024 + ((p ^ (r & 7)) << 3)),             \
            (AS3 void*)(&sA[bufidx][idx * 8]), 16, 0, 0);                                 \
    }                                                                                     \
    _Pragma("unroll") for (int it = 0; it < 4; ++it) {                                    \
        int idx = it * 512 + tid; int r = idx >> 3, p = idx & 7;                          \
        __builtin_amdgcn_global_load_lds(                                                 \
            (const AS1 void*)(Bgt + (size_t)r * 1024 + ((p ^ (r & 7)) << 3)),             \
            (AS3 void*)(&sB[bufidx][idx * 8]), 16, 0, 0);                                 \
    }                                                                                     \
} while (0)

    f32x4 acc[8][4];
#pragma unroll
    for (int i = 0; i < 8; i++)
#pragma unroll
        for (int j = 0; j < 4; j++) acc[i][j] = (f32x4){0.f, 0.f, 0.f, 0.f};

    STAGE_F(0, 0);

    for (int kt = 0; kt < 16; ++kt) {
        const int cur = kt & 1;
        if (kt < 15) {
            STAGE_F(cur ^ 1, kt + 1);
            asm volatile("s_waitcnt vmcnt(8)" ::: "memory");  // tile kt landed; kt+1 in flight
        } else {
            asm volatile("s_waitcnt vmcnt(0)" ::: "memory");
        }
        __builtin_amdgcn_s_barrier();
#pragma unroll
        for (int s = 0; s < 2; ++s) {
            bf16x8 af[8], bfv[4];
            const int ch = s * 4 + lkc;
#pragma unroll
            for (int i = 0; i < 8; i++) {
                int row = wm + i * 16 + lm;
                af[i] = *reinterpret_cast<const bf16x8*>(&sA[cur][row * 64 + ((ch ^ (row & 7)) << 3)]);
            }
#pragma unroll
            for (int j = 0; j < 4; j++) {
                int row = wn + j * 16 + lm;
                bfv[j] = *reinterpret_cast<const bf16x8*>(&sB[cur][row * 64 + ((ch ^ (row & 7)) << 3)]);
            }
            __builtin_amdgcn_s_setprio(1);
#pragma unroll
            for (int i = 0; i < 8; i++)
#pragma unroll
                for (int j = 0; j < 4; j++)
                    acc[i][j] = __builtin_amdgcn_mfma_f32_16x16x32_bf16(af[i], bfv[j], acc[i][j], 0, 0, 0);
            __builtin_amdgcn_s_setprio(0);
        }
        asm volatile("s_waitcnt lgkmcnt(0)" ::: "memory");  // all reads of buf[cur] done
        __builtin_amdgcn_s_barrier();
    }
#undef STAGE_F

    // epilogue: route columns
    const int rbase = (lane >> 4) * 4;
#pragma unroll
    for (int i = 0; i < 8; i++) {
#pragma unroll
        for (int j = 0; j < 4; j++) {
            int col = bn * 256 + wn + j * 16 + lm;
            bool isZ = (col < ZDIM);
            bool isG = (col >= 4224) && (col < 4224 + DINNER);
            bool isDT = (col >= 4096) && (col < ZDIM);
            if (!isZ && !isG) continue;
#pragma unroll
            for (int r = 0; r < 4; r++) {
                int row = bm * 256 + wm + i * 16 + rbase + r;
                float v = acc[i][j][r];
                if (isZ) {
                    z[(size_t)row * ZDIM + col] = (bf16)v;
                    if (isDT) dtout[(size_t)row * NHEADS + (col - 4096)] = v;
                } else {
                    g[(size_t)row * DINNER + (col - 4224)] = (bf16)v;
                }
            }
        }
    }
}

// ---------------- bf16 MFMA GEMM (128² m97-structure), used for the output GEMM ----------------
template<bool BF16OUT>
__global__ __launch_bounds__(256) void gemm_bf16_kernel(
    const bf16* __restrict__ A,   // [M][K] row-major
    const bf16* __restrict__ Bt,  // [Npad][K] row-major (B transposed)
    void* __restrict__ Cout,      // [M][Ns]
    int K, int Ns, int Nstore)
{
    __shared__ __align__(16) bf16 As[128 * 32];
    __shared__ __align__(16) bf16 Bs[128 * 32];
    const int t = threadIdx.x;
    const int bm = blockIdx.y, bn = blockIdx.x;
    const int w = t >> 6, lane = t & 63;
    const int wm = (w >> 1) * 64, wn = (w & 1) * 64;
    const int lm = lane & 15, lk = (lane >> 4) * 8;

    const bf16* Ab = A + (size_t)(bm * 128) * K;
    const bf16* Bb = Bt + (size_t)(bn * 128) * K;

    const int e0 = t * 8;
    const int r0s = e0 >> 5, k0s = e0 & 31;
    const int e1 = e0 + 2048;
    const int r1s = e1 >> 5, k1s = e1 & 31;

    f32x4 acc[4][4];
#pragma unroll
    for (int i = 0; i < 4; i++)
#pragma unroll
        for (int j = 0; j < 4; j++) acc[i][j] = (f32x4){0.f, 0.f, 0.f, 0.f};

    for (int k0 = 0; k0 < K; k0 += 32) {
        __builtin_amdgcn_global_load_lds(
            (const AS1 void*)(Ab + (size_t)r0s * K + k0 + k0s),
            (AS3 void*)(&As[e0]), 16, 0, 0);
        __builtin_amdgcn_global_load_lds(
            (const AS1 void*)(Ab + (size_t)r1s * K + k0 + k1s),
            (AS3 void*)(&As[e1]), 16, 0, 0);
        __builtin_amdgcn_global_load_lds(
            (const AS1 void*)(Bb + (size_t)r0s * K + k0 + k0s),
            (AS3 void*)(&Bs[e0]), 16, 0, 0);
        __builtin_amdgcn_global_load_lds(
            (const AS1 void*)(Bb + (size_t)r1s * K + k0 + k1s),
            (AS3 void*)(&Bs[e1]), 16, 0, 0);
        __syncthreads();

        bf16x8 af[4], bfr[4];
#pragma unroll
        for (int i = 0; i < 4; i++)
            af[i] = *reinterpret_cast<const bf16x8*>(&As[(wm + i * 16 + lm) * 32 + lk]);
#pragma unroll
        for (int j = 0; j < 4; j++)
            bfr[j] = *reinterpret_cast<const bf16x8*>(&Bs[(wn + j * 16 + lm) * 32 + lk]);
#pragma unroll
        for (int i = 0; i < 4; i++)
#pragma unroll
            for (int j = 0; j < 4; j++)
                acc[i][j] = __builtin_amdgcn_mfma_f32_16x16x32_bf16(af[i], bfr[j], acc[i][j], 0, 0, 0);
        __syncthreads();
    }

    const int rrow = (lane >> 4) * 4;
    const int ccol = lane & 15;
#pragma unroll
    for (int i = 0; i < 4; i++) {
#pragma unroll
        for (int j = 0; j < 4; j++) {
            int col = bn * 128 + wn + j * 16 + ccol;
            if (col < Nstore) {
#pragma unroll
                for (int r = 0; r < 4; r++) {
                    int row = bm * 128 + wm + i * 16 + rrow + r;
                    float v = acc[i][j][r];
                    if constexpr (BF16OUT)
                        ((bf16*)Cout)[(size_t)row * Ns + col] = (bf16)v;
                    else
                        ((float*)Cout)[(size_t)row * Ns + col] = v;
                }
            }
        }
    }
}

// ---------------- causal depthwise conv (D_CONV=4) + SiLU ----------------
__global__ void conv_silu_kernel(const bf16* __restrict__ z, const float* __restrict__ conv_w,
                                 const float* __restrict__ conv_b, bf16* __restrict__ x)
{
    int gid = blockIdx.x * 256 + threadIdx.x;
    if (gid >= BLROWS * DINNER) return;
    int c = gid & (DINNER - 1);
    int bl = gid >> 11;
    int l = bl & (LSEQ - 1);
    float4 w4 = *reinterpret_cast<const float4*>(conv_w + (size_t)c * 4);
    float acc = conv_b[c];
    if (l - 3 >= 0) acc += (float)z[(size_t)(bl - 3) * ZDIM + c] * w4.x;
    if (l - 2 >= 0) acc += (float)z[(size_t)(bl - 2) * ZDIM + c] * w4.y;
    if (l - 1 >= 0) acc += (float)z[(size_t)(bl - 1) * ZDIM + c] * w4.z;
    acc += (float)z[(size_t)bl * ZDIM + c] * w4.w;
    x[(size_t)gid] = (bf16)(acc / (1.f + expf(-acc)));   // silu
}

// ---------------- la = log(a_bar) = -softplus(dt+dp)*|dt| ----------------
__global__ void la_kernel(const float* __restrict__ dt_in, const float* __restrict__ dparam,
                          float* __restrict__ la)
{
    int i = blockIdx.x * 256 + threadIdx.x;
    if (i >= BLROWS * NHEADS) return;
    int h = i & (NHEADS - 1);
    float dt = dt_in[i];
    float v = dt + dparam[h];
    float sp = (v > 20.f) ? v : log1pf(expf(v));
    la[i] = -sp * fabsf(dt);
}

// ================= chunked scan, SSD matmul form =================
__global__ __launch_bounds__(256) void chunk_state_kernel(
    const bf16* __restrict__ x,    // [BL][DINNER]
    const bf16* __restrict__ zb,   // B at col DINNER+h*64, stride ZDIM
    const float* __restrict__ la,  // [BL][16] log a
    bf16* __restrict__ S,          // [B][NCHUNK][NHEADS][128*64]
    float* __restrict__ Adec)      // [B][NHEADS][NCHUNK] = exp(Ls_Q)
{
    __shared__ __align__(16) bf16 xt[HEADDIM * QCHUNK]; // [d][t] swizzled
    __shared__ __align__(16) bf16 bw[DSTATE * QCHUNK];  // [s][t] swizzled, weighted
    __shared__ float Ls[QCHUNK];
    const int blk = blockIdx.x;
    const int h = blk & 15, c = (blk >> 4) & 63, b = blk >> 10;
    const int tid = threadIdx.x, lane = tid & 63, w = tid >> 6;
    const size_t row0 = (size_t)b * LSEQ + (size_t)c * QCHUNK;
    const bf16* xg = x + row0 * DINNER + h * HEADDIM;
    const bf16* Bg = zb + row0 * ZDIM + DINNER + h * DSTATE;

    const int t = tid >> 2, dseg = (tid & 3) * 32, sseg = (tid & 3) * 16;
    bf16x8 xr[4], br[2];
#pragma unroll
    for (int q = 0; q < 4; q++)
        xr[q] = *reinterpret_cast<const bf16x8*>(xg + (size_t)t * DINNER + dseg + q * 8);
#pragma unroll
    for (int q = 0; q < 2; q++)
        br[q] = *reinterpret_cast<const bf16x8*>(Bg + (size_t)t * ZDIM + sseg + q * 8);

    if (w == 0) {
        float v = la[(row0 + lane) * NHEADS + h];
#pragma unroll
        for (int off = 1; off < 64; off <<= 1) { float o = __shfl_up(v, off); if (lane >= off) v += o; }
        Ls[lane] = v;
        if (lane == 63) Adec[((size_t)b * NHEADS + h) * NCHUNK + c] = __expf(v);
    }
    __syncthreads();
    const float wt = __expf(Ls[QCHUNK - 1] - Ls[t]);
    const int tb = t >> 3, ti = t & 7;
#pragma unroll
    for (int q = 0; q < 4; q++)
#pragma unroll
        for (int j = 0; j < 8; j++) {
            int d = dseg + q * 8 + j;
            xt[d * 64 + ((tb ^ (d & 7)) << 3) + ti] = xr[q][j];
        }
#pragma unroll
    for (int q = 0; q < 2; q++)
#pragma unroll
        for (int j = 0; j < 8; j++) {
            int s = sseg + q * 8 + j;
            bw[s * 64 + ((tb ^ (s & 7)) << 3) + ti] = (bf16)((float)br[q][j] * wt);
        }
    __syncthreads();

    f32x4 acc[2][4];
#pragma unroll
    for (int i = 0; i < 2; i++)
#pragma unroll
        for (int j = 0; j < 4; j++) acc[i][j] = (f32x4){0.f, 0.f, 0.f, 0.f};
#pragma unroll
    for (int kk = 0; kk < 2; kk++) {
        const int kb = kk * 4 + (lane >> 4);
        bf16x8 af[2], bf2[4];
#pragma unroll
        for (int i = 0; i < 2; i++) {
            int d = w * 32 + i * 16 + (lane & 15);
            af[i] = *reinterpret_cast<const bf16x8*>(&xt[d * 64 + ((kb ^ (d & 7)) << 3)]);
        }
#pragma unroll
        for (int j = 0; j < 4; j++) {
            int s = j * 16 + (lane & 15);
            bf2[j] = *reinterpret_cast<const bf16x8*>(&bw[s * 64 + ((kb ^ (s & 7)) << 3)]);
        }
#pragma unroll
        for (int i = 0; i < 2; i++)
#pragma unroll
            for (int j = 0; j < 4; j++)
                acc[i][j] = __builtin_amdgcn_mfma_f32_16x16x32_bf16(af[i], bf2[j], acc[i][j], 0, 0, 0);
    }
    bf16* Sg = S + ((size_t)(b * NCHUNK + c) * NHEADS + h) * (HEADDIM * DSTATE);
    const int rr = (lane >> 4) * 4, ccol = lane & 15;
#pragma unroll
    for (int i = 0; i < 2; i++)
#pragma unroll
        for (int j = 0; j < 4; j++)
#pragma unroll
            for (int r = 0; r < 4; r++)
                Sg[(w * 32 + i * 16 + rr + r) * 64 + j * 16 + ccol] = (bf16)acc[i][j][r];
}

// Pass 1b: inter-chunk carry, in-place: S_c -> H_c (state at chunk START).
__global__ void chunk_carry_kernel(bf16* S, const float* __restrict__ A)
{
    int gid = blockIdx.x * 256 + threadIdx.x;
    if (gid >= BATCH * NHEADS * HEADDIM * DSTATE) return;
    int es = gid & (HEADDIM * DSTATE - 1);
    int h  = (gid >> 13) & (NHEADS - 1);
    int b  = gid >> 17;
    const float* Ab = A + ((size_t)b * NHEADS + h) * NCHUNK;
    float hstate = 0.f;
    size_t stride = (size_t)NHEADS * HEADDIM * DSTATE;
    bf16* p = S + ((size_t)b * NCHUNK * NHEADS + h) * (HEADDIM * DSTATE) + es;
    for (int c = 0; c < NCHUNK; ++c) {
        float sv = (float)*p;
        *p = (bf16)hstate;
        hstate = fmaf(Ab[c], hstate, sv);
        p += stride;
    }
}

// Pass 2: Y^T[d][t] = [Xt | H] @ [MG | P.C]^T  (K = 64 t' + 64 s), in-place over X.
__global__ __launch_bounds__(256) void chunk_y_kernel(
    bf16* xy,                       // [BL][DINNER]: x in, y out (same storage)
    const bf16* __restrict__ zb,    // B/C in z, stride ZDIM
    const float* __restrict__ la,   // [BL][16] log a
    const bf16* __restrict__ H)     // [B][NCHUNK][NHEADS][128*64] chunk-start state
{
    __shared__ __align__(16) bf16 bc[QCHUNK * 128];    // B | C, later MG[64][128]
    __shared__ __align__(16) bf16 xt[HEADDIM * QCHUNK];
    __shared__ __align__(16) bf16 hl[HEADDIM * DSTATE];
    __shared__ float Ls[QCHUNK];
    const int blk = blockIdx.x;
    const int h = blk & 15, c = (blk >> 4) & 63, b = blk >> 10;
    const int tid = threadIdx.x, lane = tid & 63, w = tid >> 6;
    const size_t row0 = (size_t)b * LSEQ + (size_t)c * QCHUNK;
    bf16* xg = xy + row0 * DINNER + h * HEADDIM;
    const bf16* Bg = zb + row0 * ZDIM + DINNER + h * DSTATE;
    const bf16* Cg = Bg + NHEADS * DSTATE;
    const bf16* Hg = H + ((size_t)(b * NCHUNK + c) * NHEADS + h) * (HEADDIM * DSTATE);

#pragma unroll
    for (int it = 0; it < 2; it++) {
        int idx = it * 256 + tid;
        int row = idx >> 3, p = idx & 7;
        int sc = (p ^ (row & 7)) << 3;
        __builtin_amdgcn_global_load_lds((const AS1 void*)(Bg + (size_t)row * ZDIM + sc),
                                         (AS3 void*)(&bc[idx * 8]), 16, 0, 0);
        __builtin_amdgcn_global_load_lds((const AS1 void*)(Cg + (size_t)row * ZDIM + sc),
                                         (AS3 void*)(&bc[4096 + idx * 8]), 16, 0, 0);
    }
#pragma unroll
    for (int it = 0; it < 4; it++) {
        int idx = it * 256 + tid;
        int d = idx >> 3, p = idx & 7;
        __builtin_amdgcn_global_load_lds((const AS1 void*)(Hg + d * 64 + ((p ^ (d & 7)) << 3)),
                                         (AS3 void*)(&hl[idx * 8]), 16, 0, 0);
    }
    const int t = tid >> 2, dseg = (tid & 3) * 32, sseg = (tid & 3) * 16;
    bf16x8 xr[4];
#pragma unroll
    for (int q = 0; q < 4; q++)
        xr[q] = *reinterpret_cast<const bf16x8*>(xg + (size_t)t * DINNER + dseg + q * 8);
    if (w == 0) {
        float v = la[(row0 + lane) * NHEADS + h];
#pragma unroll
        for (int off = 1; off < 64; off <<= 1) { float o = __shfl_up(v, off); if (lane >= off) v += o; }
        Ls[lane] = v;
    }
    __syncthreads();

    const int tb = t >> 3, ti = t & 7;
#pragma unroll
    for (int q = 0; q < 4; q++)
#pragma unroll
        for (int j = 0; j < 8; j++) {
            int d = dseg + q * 8 + j;
            xt[d * 64 + ((tb ^ (d & 7)) << 3) + ti] = xr[q][j];
        }

    f32x4 g[4];
#pragma unroll
    for (int j = 0; j < 4; j++) g[j] = (f32x4){0.f, 0.f, 0.f, 0.f};
#pragma unroll
    for (int kk = 0; kk < 2; kk++) {
        const int kb = kk * 4 + (lane >> 4);
        const int tA = w * 16 + (lane & 15);
        bf16x8 ca = *reinterpret_cast<const bf16x8*>(&bc[4096 + tA * 64 + ((kb ^ (tA & 7)) << 3)]);
#pragma unroll
        for (int j = 0; j < 4; j++) {
            int tB = j * 16 + (lane & 15);
            bf16x8 bb = *reinterpret_cast<const bf16x8*>(&bc[tB * 64 + ((kb ^ (tB & 7)) << 3)]);
            g[j] = __builtin_amdgcn_mfma_f32_16x16x32_bf16(ca, bb, g[j], 0, 0, 0);
        }
    }
    bf16x8 cr[2];
#pragma unroll
    for (int q = 0; q < 2; q++) {
        int sblk = (sseg >> 3) + q;
        cr[q] = *reinterpret_cast<const bf16x8*>(&bc[4096 + t * 64 + ((sblk ^ (t & 7)) << 3)]);
    }
    const float pscale = __expf(Ls[t]);
    __syncthreads();

    {
        const int tpbase = lane & 15;
        const int tgbase = w * 16 + (lane >> 4) * 4;
        float lst[4];
#pragma unroll
        for (int r = 0; r < 4; r++) lst[r] = Ls[tgbase + r];
#pragma unroll
        for (int j = 0; j < 4; j++) {
            int tp = j * 16 + tpbase;
            float lstp = Ls[tp];
#pragma unroll
            for (int r = 0; r < 4; r++) {
                int tg = tgbase + r;
                float mg = (tp <= tg) ? g[j][r] * __expf(lst[r] - lstp) : 0.f;
                bc[tg * 128 + (((tp >> 3) ^ (tg & 7)) << 3) + (tp & 7)] = (bf16)mg;
            }
        }
    }
#pragma unroll
    for (int q = 0; q < 2; q++) {
        int sblk = (sseg >> 3) + q;
        bf16x8 o;
#pragma unroll
        for (int j = 0; j < 8; j++) o[j] = (bf16)((float)cr[q][j] * pscale);
        *reinterpret_cast<bf16x8*>(&bc[t * 128 + ((8 + (sblk ^ (t & 7))) << 3)]) = o;
    }
    __syncthreads();

    f32x4 acc[2][4];
#pragma unroll
    for (int i = 0; i < 2; i++)
#pragma unroll
        for (int j = 0; j < 4; j++) acc[i][j] = (f32x4){0.f, 0.f, 0.f, 0.f};
#pragma unroll
    for (int kk = 0; kk < 4; kk++) {
        const int kb = kk * 4 + (lane >> 4);
        bf16x8 af[2];
#pragma unroll
        for (int i = 0; i < 2; i++) {
            int d = w * 32 + i * 16 + (lane & 15);
            if (kk < 2)
                af[i] = *reinterpret_cast<const bf16x8*>(&xt[d * 64 + ((kb ^ (d & 7)) << 3)]);
            else
                af[i] = *reinterpret_cast<const bf16x8*>(&hl[d * 64 + (((kb - 8) ^ (d & 7)) << 3)]);
        }
#pragma unroll
        for (int j = 0; j < 4; j++) {
            int tt = j * 16 + (lane & 15);
            bf16x8 b2 = *reinterpret_cast<const bf16x8*>(&bc[tt * 128 + ((kb ^ (tt & 7)) << 3)]);
#pragma unroll
            for (int i = 0; i < 2; i++)
                acc[i][j] = __builtin_amdgcn_mfma_f32_16x16x32_bf16(af[i], b2, acc[i][j], 0, 0, 0);
        }
    }
#pragma unroll
    for (int i = 0; i < 2; i++)
#pragma unroll
        for (int j = 0; j < 4; j++) {
            int d0 = w * 32 + i * 16 + (lane >> 4) * 4;
            int tt = j * 16 + (lane & 15);
            bf16x4 o;
#pragma unroll
            for (int r = 0; r < 4; r++) o[r] = (bf16)acc[i][j][r];
            *reinterpret_cast<bf16x4*>(xg + (size_t)tt * DINNER + d0) = o;
        }
}

// ---------------- gate (sigmoid) * y, RMS norm, -> bf16 (in-place over g) ----------------
__global__ __launch_bounds__(256) void gate_rms_kernel(
    const bf16* __restrict__ y,   // [BL][2048]
    bf16* g,                      // [BL][2048]: gate pre-act in, normalized y out
    const float* __restrict__ norm_w)
{
    __shared__ float red[4];
    int row = blockIdx.x, t = threadIdx.x;
    const bf16* yr = y + (size_t)row * DINNER;
    bf16* gr = g + (size_t)row * DINNER;
    int c0 = t * 8;
    bf16x8 yv8 = *reinterpret_cast<const bf16x8*>(yr + c0);
    bf16x8 gv8 = *reinterpret_cast<const bf16x8*>(gr + c0);
    float v[8];
#pragma unroll
    for (int i = 0; i < 8; i++) {
        float yf = (float)yv8[i];
        float gf = (float)gv8[i];
        v[i] = yf / (1.f + expf(-gf));
    }
    float ss = 0.f;
#pragma unroll
    for (int i = 0; i < 8; i++) ss += v[i] * v[i];
#pragma unroll
    for (int off = 32; off >= 1; off >>= 1) ss += __shfl_xor(ss, off);
    if ((t & 63) == 0) red[t >> 6] = ss;
    __syncthreads();
    ss = red[0] + red[1] + red[2] + red[3];
    float sc = rsqrtf(ss * (1.0f / DINNER) + 1.1920928955078125e-07f);
    float4 na = *reinterpret_cast<const float4*>(norm_w + c0);
    float4 nb = *reinterpret_cast<const float4*>(norm_w + c0 + 4);
    bf16x8 ov;
    ov[0] = (bf16)(v[0] * sc * na.x);
    ov[1] = (bf16)(v[1] * sc * na.y);
    ov[2] = (bf16)(v[2] * sc * na.z);
    ov[3] = (bf16)(v[3] * sc * na.w);
    ov[4] = (bf16)(v[4] * sc * nb.x);
    ov[5] = (bf16)(v[5] * sc * nb.y);
    ov[6] = (bf16)(v[6] * sc * nb.z);
    ov[7] = (bf16)(v[7] * sc * nb.w);
    *reinterpret_cast<bf16x8*>(gr + c0) = ov;
}

// ---------------- launch ----------------
extern "C" void kernel_launch(void* const* d_in, const int* in_sizes, int n_in,
                              void* d_out, int out_size, void* d_ws, size_t ws_size,
                              hipStream_t stream)
{
    const float* u      = (const float*)d_in[0];
    const float* W_in   = (const float*)d_in[1];
    const float* conv_w = (const float*)d_in[2];
    const float* conv_b = (const float*)d_in[3];
    const float* dparam = (const float*)d_in[4];
    const float* W_gate = (const float*)d_in[5];
    const float* norm_w = (const float*)d_in[6];
    const float* W_out  = (const float*)d_in[7];
    float* out = (float*)d_out;

    char* ws = (char*)d_ws;
    size_t off = 0;
    auto alloc = [&](size_t bytes) {
        void* p = ws + off;
        off += (bytes + 255) & ~(size_t)255;
        return p;
    };
    // total ws use: ~170 MB
    bf16*  u_bf  = (bf16*) alloc((size_t)BLROWS * DMODEL * 2);   // 16.8 MB
    bf16*  Wt_f  = (bf16*) alloc((size_t)NFUSE * DMODEL * 2);    // 13.1 MB (W_in | pad | W_gate | pad)
    bf16*  Wt_o  = (bf16*) alloc((size_t)DMODEL * DINNER * 2);   // 4.2 MB
    bf16*  z     = (bf16*) alloc((size_t)BLROWS * ZDIM * 2);     // 67.4 MB
    bf16*  g     = (bf16*) alloc((size_t)BLROWS * DINNER * 2);   // 33.6 MB (yn in-place)
    float* dt    = (float*)alloc((size_t)BLROWS * NHEADS * 4);   // 0.5 MB
    float* lab   = (float*)alloc((size_t)BLROWS * NHEADS * 4);   // 0.5 MB (log a)
    bf16*  S     = (bf16*) alloc((size_t)BATCH * NCHUNK * NHEADS * HEADDIM * DSTATE * 2); // 33.6 MB
    float* Adec  = (float*)alloc((size_t)BATCH * NHEADS * NCHUNK * 4);                    // 8 KB
    bf16* xy = (bf16*)d_out;   // x/y live in d_out, fully overwritten by final GEMM
    (void)ws_size; (void)in_sizes; (void)n_in; (void)out_size;

    dim3 tb(32, 8);
    cvt_bf16_kernel<<<(BLROWS * DMODEL / 4 + 255) / 256, 256, 0, stream>>>(u, u_bf, BLROWS * DMODEL);
    // fused weight: rows 0..4111 = W_in^T, 4112..4223 = 0, 4224..6271 = W_gate^T, 6272..6399 = 0
    transpose_cvt_kernel<<<dim3(4224 / 32, DMODEL / 32), tb, 0, stream>>>(W_in, Wt_f, DMODEL, ZDIM, 4224);
    transpose_cvt_kernel<<<dim3(2176 / 32, DMODEL / 32), tb, 0, stream>>>(W_gate, Wt_f + (size_t)4224 * DMODEL, DMODEL, DINNER, 2176);
    transpose_cvt_kernel<<<dim3(DMODEL / 32, DINNER / 32), tb, 0, stream>>>(W_out, Wt_o, DINNER, DMODEL, DMODEL);

    // fused z|g GEMM: M=8192, K=1024, N=6400
    gemm_fused_kernel<<<(BLROWS / 256) * (NFUSE / 256), 512, 0, stream>>>(u_bf, Wt_f, z, g, dt);

    conv_silu_kernel<<<(BLROWS * DINNER + 255) / 256, 256, 0, stream>>>(z, conv_w, conv_b, xy);
    la_kernel<<<(BLROWS * NHEADS + 255) / 256, 256, 0, stream>>>(dt, dparam, lab);

    // chunked scan (SSD matmul form)
    chunk_state_kernel<<<BATCH * NCHUNK * NHEADS, 256, 0, stream>>>(xy, z, lab, S, Adec);
    chunk_carry_kernel<<<(BATCH * NHEADS * HEADDIM * DSTATE) / 256, 256, 0, stream>>>(S, Adec);
    chunk_y_kernel<<<BATCH * NCHUNK * NHEADS, 256, 0, stream>>>(xy, z, lab, S);

    gate_rms_kernel<<<BLROWS, 256, 0, stream>>>(xy, g, norm_w);

    // out = yn @ W_out (f32 out)   M=8192, K=2048, N=1024 — overwrites xy region
    gemm_bf16_kernel<false><<<dim3(DMODEL / 128, BLROWS / 128), 256, 0, stream>>>(
        g, Wt_o, out, DINNER, DMODEL, DMODEL);
}